// Round 9
// baseline (654.514 us; speedup 1.0000x reference)
//
#include <hip/hip_runtime.h>
#include <cstdio>
#include <cstddef>
#include <cstdint>

#define F_B 8
#define F_C 256
#define F_H 128
#define F_W 128
#define F_HW 16384

typedef __attribute__((ext_vector_type(8))) short short8;   // bf16x8 MFMA operand
typedef __attribute__((ext_vector_type(4))) short short4v;  // bf16x4
typedef __attribute__((ext_vector_type(4))) float float4v;  // MFMA accumulator

__device__ __forceinline__ unsigned short f2bf(float f) {
  union {
    float f;
    uint32_t u;
  } v;
  v.f = f;
  return (unsigned short)((v.u + 0x7fffu + ((v.u >> 16) & 1u)) >> 16);
}

__device__ __forceinline__ float bf2f(unsigned short u) {
  union {
    uint32_t u;
    float f;
  } v;
  v.u = ((uint32_t)u) << 16;
  return v.f;
}

__device__ __forceinline__ void async_copy16(const unsigned short* g, unsigned short* l) {
  __builtin_amdgcn_global_load_lds((const __attribute__((address_space(1))) void*)g,
                                   (__attribute__((address_space(3))) void*)l, 16, 0, 0);
}

// ---------------- aux: weight bf16 conversion + bias concat ----------------
__global__ void build_aux2(const float* __restrict__ Wq, const float* __restrict__ Wk,
                           const float* __restrict__ bq, const float* __restrict__ bk,
                           const float* __restrict__ q_bias, const float* __restrict__ v_bias,
                           const float* __restrict__ Wv, const float* __restrict__ qkv_w,
                           const float* __restrict__ proj_w, unsigned short* __restrict__ qk_wb,
                           float* __restrict__ qk_b, float* __restrict__ qkv_b,
                           unsigned short* __restrict__ Wvb, unsigned short* __restrict__ qkv_wb,
                           unsigned short* __restrict__ proj_wb) {
  int t = blockIdx.x * 256 + threadIdx.x;  // 768 blocks -> 196608 threads
  if (t < 8192) {
    qk_wb[t] = f2bf(Wq[t]);
    qk_wb[8192 + t] = f2bf(Wk[t]);
  }
  if (t < 65536) {
    Wvb[t] = f2bf(Wv[t]);
    proj_wb[t] = f2bf(proj_w[t]);
  }
  if (t < 196608) qkv_wb[t] = f2bf(qkv_w[t]);
  if (t < 32) {
    qk_b[t] = bq[t];
    qk_b[32 + t] = bk[t];
  }
  if (t < 256) {
    qkv_b[t] = q_bias[t];
    qkv_b[256 + t] = 0.0f;
    qkv_b[512 + t] = v_bias[t];
  }
}

// ---------------- CPB MLP table: tblS[225][8] = 16*sigmoid(mlp(coords)) -----
__device__ __forceinline__ float cpb_coord(int a) {
  float v = (float)(a - 7) * (8.0f / 7.0f);
  float lg = log2f(fabsf(v) + 1.0f) * (1.0f / 3.0f);  // /log2(8)
  return (v < 0.0f) ? -lg : lg;
}

__global__ void cpb_table(const float* __restrict__ w1, const float* __restrict__ b1,
                          const float* __restrict__ w2, float* __restrict__ tblS) {
  int e = blockIdx.x;  // 0..224
  int yi = e / 15, xi = e % 15;
  float ry = cpb_coord(yi), rx = cpb_coord(xi);
  __shared__ float hid[512];
  int t = threadIdx.x;  // 256
  for (int j = t; j < 512; j += 256) {
    float hv = w1[j * 2] * ry + w1[j * 2 + 1] * rx + b1[j];
    hid[j] = fmaxf(hv, 0.0f);
  }
  __syncthreads();
  if (t < 8) {
    float s = 0.0f;
    for (int j = 0; j < 512; j++) s += hid[j] * w2[t * 512 + j];
    tblS[e * 8 + t] = 16.0f / (1.0f + __expf(-s));
  }
}

// ---------------- rpbt[h][i][j] = tblS[e(i,j)*8+h]  (window-independent) ----
__global__ void build_rpbt(const float* __restrict__ tblS, float* __restrict__ rpbt) {
  int t = blockIdx.x * 256 + threadIdx.x;  // < 32768
  int h = t >> 12, i = (t >> 6) & 63, j = t & 63;
  int e = ((i >> 3) - (j >> 3) + 7) * 15 + ((i & 7) - (j & 7) + 7);
  rpbt[t] = tblS[e * 8 + h];
}

// ---------------- transpose (B,C,HW) -> (B,HW,C) bf16, short4 stores -------
__global__ void transpose_bf(const float* __restrict__ in, unsigned short* __restrict__ outb) {
  __shared__ float tile[32][33];
  int b = blockIdx.z;
  int p0 = blockIdx.x * 32;
  int c0 = blockIdx.y * 32;
  const float* src = in + (size_t)b * F_C * F_HW;
  int t = threadIdx.x;
  int tx = t & 31, ty = t >> 5;  // tx = pixel, ty = channel-base (8)
#pragma unroll
  for (int i = 0; i < 4; i++) {
    tile[ty + i * 8][tx] = src[(size_t)(c0 + ty + i * 8) * F_HW + p0 + tx];
  }
  __syncthreads();
  int pix = t >> 3, cl = (t & 7) * 4;
  short4v pk;
#pragma unroll
  for (int u = 0; u < 4; u++) pk[u] = (short)f2bf(tile[cl + u][pix]);
  size_t idx = (size_t)b * F_HW * F_C + (size_t)(p0 + pix) * F_C + c0 + cl;
  *(short4v*)(outb + idx) = pk;
}

// ---------------- bf16 MFMA GEMM: C[M,N] = A[M,256] @ W[N,256]^T + bias ----
// 1-D grid with XCD-chunked swizzle (gridDim.x % 8 == 0, x-fast within chunk).
// For OUT!=1 the MFMA operands are SWAPPED (D = C^T fragments): each lane then
// holds 4 consecutive COLUMNS of one row -> 8B/16B epilogue stores instead of
// 64 scattered 2B stores. OUT==1 keeps the row-fragment layout (its transposed
// write is contiguous along rows).
// OUT 0: fp32 row-major. OUT 1: fp32 out[((row>>14)*N+col)*16384+(row&16383)].
// OUT 2: bf16 row-major.
template <int BN, int OUT>
__global__ __launch_bounds__(256) void gemm_mfma(const unsigned short* __restrict__ A,
                                                 const unsigned short* __restrict__ Wt,
                                                 const float* __restrict__ bias, void* Cmat,
                                                 int M, int N, int gx) {
  constexpr int WN = BN / 2;
  constexpr int NREP = WN / 16;
  __shared__ __align__(16) unsigned short As[128 * 32];
  __shared__ __align__(16) unsigned short Bs[BN * 32];
  int nwg = gridDim.x;
  int id = blockIdx.x;
  int cpx = nwg >> 3;
  int swz = (id & 7) * cpx + (id >> 3);
  int by = swz / gx;
  int bx = swz - by * gx;
  int m0 = by * 128;
  int n0 = bx * BN;
  int t = threadIdx.x;
  int wid = t >> 6, lane = t & 63;
  int wr = wid >> 1, wc = wid & 1;

  float4v acc[4][NREP] = {};

  for (int k0 = 0; k0 < 256; k0 += 32) {
    __syncthreads();
#pragma unroll
    for (int j = 0; j < 2; j++) {
      int r = wid * 32 + j * 16 + (lane >> 2);
      int kg = (lane & 3) ^ ((r >> 1) & 3);  // inverse swizzle on global source
      const unsigned short* gp = A + (size_t)(m0 + r) * 256 + k0 + kg * 8;
      async_copy16(gp, As + (wid * 32 + j * 16) * 32);
    }
#pragma unroll
    for (int j = 0; j < BN / 64; j++) {
      int r = wid * (BN / 4) + j * 16 + (lane >> 2);
      int kg = (lane & 3) ^ ((r >> 1) & 3);
      const unsigned short* gp = Wt + (size_t)(n0 + r) * 256 + k0 + kg * 8;
      async_copy16(gp, Bs + (wid * (BN / 4) + j * 16) * 32);
    }
    __syncthreads();
    short8 af[4];
#pragma unroll
    for (int mi = 0; mi < 4; mi++) {
      int row = wr * 64 + mi * 16 + (lane & 15);
      int kg = (lane >> 4) ^ ((row >> 1) & 3);
      af[mi] = *(const short8*)(As + row * 32 + kg * 8);
    }
    short8 bfr[NREP];
#pragma unroll
    for (int ni = 0; ni < NREP; ni++) {
      int col = wc * WN + ni * 16 + (lane & 15);
      int kg = (lane >> 4) ^ ((col >> 1) & 3);
      bfr[ni] = *(const short8*)(Bs + col * 32 + kg * 8);
    }
#pragma unroll
    for (int mi = 0; mi < 4; mi++)
#pragma unroll
      for (int ni = 0; ni < NREP; ni++) {
        if (OUT != 1)
          acc[mi][ni] =
              __builtin_amdgcn_mfma_f32_16x16x32_bf16(bfr[ni], af[mi], acc[mi][ni], 0, 0, 0);
        else
          acc[mi][ni] =
              __builtin_amdgcn_mfma_f32_16x16x32_bf16(af[mi], bfr[ni], acc[mi][ni], 0, 0, 0);
      }
  }
  if (OUT != 1) {
    // swapped: lane holds row = ..+(lane&15) fixed, 4 consecutive cols
#pragma unroll
    for (int mi = 0; mi < 4; mi++) {
      int row = m0 + wr * 64 + mi * 16 + (lane & 15);
#pragma unroll
      for (int ni = 0; ni < NREP; ni++) {
        int col0 = n0 + wc * WN + ni * 16 + (lane >> 4) * 4;
        float4 bn = *(const float4*)(bias + col0);
        float v0 = acc[mi][ni][0] + bn.x;
        float v1 = acc[mi][ni][1] + bn.y;
        float v2 = acc[mi][ni][2] + bn.z;
        float v3 = acc[mi][ni][3] + bn.w;
        if (OUT == 0) {
          float4 st = {v0, v1, v2, v3};
          *(float4*)((float*)Cmat + (size_t)row * N + col0) = st;
        } else {
          short4v pk;
          pk[0] = (short)f2bf(v0);
          pk[1] = (short)f2bf(v1);
          pk[2] = (short)f2bf(v2);
          pk[3] = (short)f2bf(v3);
          *(short4v*)((unsigned short*)Cmat + (size_t)row * N + col0) = pk;
        }
      }
    }
  } else {
#pragma unroll
    for (int ni = 0; ni < NREP; ni++) {
      int col = n0 + wc * WN + ni * 16 + (lane & 15);
      float bn = bias[col];
#pragma unroll
      for (int mi = 0; mi < 4; mi++) {
        int row0 = m0 + wr * 64 + mi * 16 + (lane >> 4) * 4;
        float4 st;
        st.x = acc[mi][ni][0] + bn;
        st.y = acc[mi][ni][1] + bn;
        st.z = acc[mi][ni][2] + bn;
        st.w = acc[mi][ni][3] + bn;
        int bb = row0 >> 14, p = row0 & 16383;
        *(float4*)((float*)Cmat + ((size_t)bb * N + col) * F_HW + p) = st;
      }
    }
  }
}

// ---------------- criss-cross logits (bf16 exp output + partial row sum) ----
// MODE 0 (H/column): block (w=x, b); E[h,g] = q(h,x)·k(g,x); e[pix(h,x)][g], diag->0
// MODE 1 (W/row):    block (h=x, b); E[w,v] = q(x,w)·k(x,v); e[pix(x,w)][128+v]
// sums[pix] = sum over this mode's 128 exps.
template <int MODE>
__global__ __launch_bounds__(256) void cc_logits(const float* __restrict__ qk,
                                                 unsigned short* __restrict__ e,
                                                 float* __restrict__ sums) {
  int x = blockIdx.x;
  int b = blockIdx.y;
  size_t base = (size_t)b * F_HW;
  __shared__ float kt[32][132];  // kt[c][g]
  int t = threadIdx.x;
  {
    int gk = t >> 1, c0 = (t & 1) * 16;
    size_t krow = (MODE == 0) ? ((size_t)gk * F_W + x) : ((size_t)x * F_W + gk);
    const float4* src = (const float4*)(qk + (base + krow) * 64 + 32 + c0);
#pragma unroll
    for (int q4 = 0; q4 < 4; q4++) {
      float4 v = src[q4];
      kt[c0 + q4 * 4 + 0][gk] = v.x;
      kt[c0 + q4 * 4 + 1][gk] = v.y;
      kt[c0 + q4 * 4 + 2][gk] = v.z;
      kt[c0 + q4 * 4 + 3][gk] = v.w;
    }
  }
  __syncthreads();
  int i = t >> 1, g0 = (t & 1) * 64;
  size_t qrow = (MODE == 0) ? ((size_t)i * F_W + x) : ((size_t)x * F_W + i);
  const float4* qp = (const float4*)(qk + (base + qrow) * 64);
  float qreg[32];
#pragma unroll
  for (int q4 = 0; q4 < 8; q4++) {
    float4 v = qp[q4];
    qreg[q4 * 4 + 0] = v.x;
    qreg[q4 * 4 + 1] = v.y;
    qreg[q4 * 4 + 2] = v.z;
    qreg[q4 * 4 + 3] = v.w;
  }
  float acc[64];
#pragma unroll
  for (int g = 0; g < 64; g++) acc[g] = 0.0f;
  for (int c = 0; c < 32; c++) {
    float qv = qreg[c];
#pragma unroll
    for (int g = 0; g < 64; g++) acc[g] += qv * kt[c][g0 + g];
  }
  if (MODE == 0) {
    int d = i - g0;
    if (d >= 0 && d < 64) acc[d] = -1e9f;  // diag mask -> exp = 0
  }
  unsigned short* ep = e + (base + qrow) * 256 + MODE * 128 + g0;
  float s = 0.0f;
#pragma unroll
  for (int g = 0; g < 64; g += 8) {
    short8 pk;
#pragma unroll
    for (int j = 0; j < 8; j++) {
      float ev = __expf(acc[g + j]);
      s += ev;
      pk[j] = (short)f2bf(ev);
    }
    *(short8*)(ep + g) = pk;
  }
  s += __shfl_xor(s, 1);  // pair (t, t^1) share the same row i
  if ((t & 1) == 0) sums[base + qrow] = s;
}

// ---------------- criss-cross PV, bf16 MFMA (swapped operands) ----------------
// O[i][c] = sum_k Anorm[i][k] * V[k][c] per (x,b) block; 128x256x128.
// Swapped MFMA: lane holds fixed i, 4 consecutive c -> 8B loads/stores.
// MODE 0: i=h (col x fixed), k=g, pix(i)=i*128+x  -> writes pob = bf16 raw oH
// MODE 1: i=w (row x fixed), k=v, pix(i)=x*128+i  -> ccb = bf16(gm*(po+oW)+x)
template <int MODE>
__global__ __launch_bounds__(256) void cc_pv_mfma(const unsigned short* __restrict__ eb,
                                                  const unsigned short* __restrict__ vtb,
                                                  const float* __restrict__ sumH,
                                                  const float* __restrict__ sumW,
                                                  const float* __restrict__ gamma,
                                                  const unsigned short* __restrict__ xb,
                                                  unsigned short* __restrict__ pob,
                                                  unsigned short* __restrict__ ccb) {
  int x = blockIdx.x, b = blockIdx.y;
  size_t base = (size_t)b * F_HW;
  __shared__ __align__(16) unsigned short As[128 * 128];  // [i][k], swizzled, 32 KB
  __shared__ __align__(16) unsigned short Vs[256 * 64];   // [c][k-chunk], swizzled, 32 KB
  int t = threadIdx.x;
  int wid = t >> 6, lane = t & 63;
  int wr = wid >> 1, wc = wid & 1;
  // ---- stage A = normalized e (bf16) ----
  {
    int i = t >> 1, half = t & 1;
    size_t pix = (MODE == 0) ? ((size_t)i * F_W + x) : ((size_t)x * F_W + i);
    float rv = 1.0f / (sumH[base + pix] + sumW[base + pix]);
    const unsigned short* ep = eb + (base + pix) * 256 + MODE * 128 + half * 64;
    int g = ((i >> 3) & 7) ^ (i & 7);
#pragma unroll
    for (int s = 0; s < 8; s++) {
      short8 vin = *(const short8*)(ep + s * 8);
      short8 vo;
#pragma unroll
      for (int j = 0; j < 8; j++) vo[j] = (short)f2bf(bf2f((unsigned short)vin[j]) * rv);
      int slot = (half * 8 + s) ^ g;  // g is 3-bit: half bit preserved
      *(short8*)(As + i * 128 + slot * 8) = vo;
    }
  }
  float4v acc[4][8] = {};
#pragma unroll
  for (int kc = 0; kc < 2; kc++) {
    __syncthreads();
    // ---- stage Vs[c][k] for k-chunk kc: in-register 8x8 transpose ----
    {
      int ko = t >> 5, cj = t & 31;
      short8 rowv[8];
#pragma unroll
      for (int r = 0; r < 8; r++) {
        int kk = kc * 64 + ko * 8 + r;
        size_t pixk = (MODE == 0) ? ((size_t)kk * F_W + x) : ((size_t)x * F_W + kk);
        rowv[r] = *(const short8*)(vtb + (base + pixk) * 256 + cj * 8);
      }
#pragma unroll
      for (int j = 0; j < 8; j++) {
        short8 col;
#pragma unroll
        for (int r = 0; r < 8; r++) col[r] = rowv[r][j];
        int c = cj * 8 + j;
        int slot = ko ^ ((c >> 3) & 7) ^ (c & 7);
        *(short8*)(Vs + c * 64 + slot * 8) = col;
      }
    }
    __syncthreads();
#pragma unroll
    for (int ksub = 0; ksub < 2; ksub++) {
      short8 af[4];
#pragma unroll
      for (int mi = 0; mi < 4; mi++) {
        int i = wr * 64 + mi * 16 + (lane & 15);
        int slot = (kc * 8 + ksub * 4 + (lane >> 4)) ^ ((i >> 3) & 7) ^ (i & 7);
        af[mi] = *(const short8*)(As + i * 128 + slot * 8);
      }
      short8 bfv[8];
#pragma unroll
      for (int ni = 0; ni < 8; ni++) {
        int c = wc * 128 + ni * 16 + (lane & 15);
        int slot = (ksub * 4 + (lane >> 4)) ^ ((c >> 3) & 7) ^ (c & 7);
        bfv[ni] = *(const short8*)(Vs + c * 64 + slot * 8);
      }
#pragma unroll
      for (int mi = 0; mi < 4; mi++)
#pragma unroll
        for (int ni = 0; ni < 8; ni++)
          acc[mi][ni] =
              __builtin_amdgcn_mfma_f32_16x16x32_bf16(bfv[ni], af[mi], acc[mi][ni], 0, 0, 0);
    }
  }
  // ---- epilogue: lane holds fixed i, 4 consecutive c ----
  float gm = gamma[0];
#pragma unroll
  for (int mi = 0; mi < 4; mi++) {
    int i = wr * 64 + mi * 16 + (lane & 15);
    size_t pix = (MODE == 0) ? ((size_t)i * F_W + x) : ((size_t)x * F_W + i);
    size_t rowb = (base + pix) * 256;
#pragma unroll
    for (int ni = 0; ni < 8; ni++) {
      int c0 = wc * 128 + ni * 16 + (lane >> 4) * 4;
      if (MODE == 0) {
        short4v pk;
#pragma unroll
        for (int r = 0; r < 4; r++) pk[r] = (short)f2bf(acc[mi][ni][r]);
        *(short4v*)(pob + rowb + c0) = pk;
      } else {
        short4v po4 = *(const short4v*)(pob + rowb + c0);
        short4v xb4 = *(const short4v*)(xb + rowb + c0);
        short4v pk;
#pragma unroll
        for (int r = 0; r < 4; r++)
          pk[r] = (short)f2bf(gm * (bf2f((unsigned short)po4[r]) + acc[mi][ni][r]) +
                              bf2f((unsigned short)xb4[r]));
        *(short4v*)(ccb + rowb + c0) = pk;
      }
    }
  }
}

// ---------------- window attention, MFMA: 1 wave per (window, head) --------
// qkv: [NPX][768] bf16 (q|k|v, head-major 32). out: [NPX][256] bf16.
// rpbt: [8][64][64] fp32 = 16*sigmoid(cpb) per (head, i, j).
__global__ __launch_bounds__(256) void win_attn_mfma(const unsigned short* __restrict__ qkv,
                                                     const float* __restrict__ logit_scale,
                                                     const float* __restrict__ rpbt,
                                                     unsigned short* __restrict__ out) {
  __shared__ __align__(16) unsigned short Pl[4][4096];  // per-wave P[i][j] bf16, swizzled
  __shared__ __align__(16) unsigned short Vt[4][2048];  // per-wave V^T[d][j] bf16, swizzled
  int win = blockIdx.x;
  int wid = threadIdx.x >> 6, lane = threadIdx.x & 63;
  int hh = blockIdx.y * 4 + wid;
  int b = win >> 8, wy = (win >> 4) & 15, wx = win & 15;
  size_t pbase = (size_t)b * F_HW + (size_t)(wy * 8) * F_W + wx * 8;
  int il = lane & 15, kg = lane >> 4;

  // ---- load + cosine-normalize Q (B-frags) and K (A-frags) ----
  short8 qb[4], ka[4];
#pragma unroll
  for (int ni = 0; ni < 4; ni++) {
    int i = ni * 16 + il;
    size_t row = (pbase + (size_t)(i >> 3) * F_W + (i & 7)) * 768 + hh * 32 + kg * 8;
    short8 qv = *(const short8*)(qkv + row);
    short8 kv = *(const short8*)(qkv + row + 256);
    float qss = 0.0f, kss = 0.0f;
#pragma unroll
    for (int j = 0; j < 8; j++) {
      float qf = bf2f((unsigned short)qv[j]);
      float kf = bf2f((unsigned short)kv[j]);
      qss += qf * qf;
      kss += kf * kf;
    }
    qss += __shfl_xor(qss, 16);
    qss += __shfl_xor(qss, 32);
    kss += __shfl_xor(kss, 16);
    kss += __shfl_xor(kss, 32);
    float qinv = 1.0f / fmaxf(sqrtf(qss), 1e-12f);
    float kinv = 1.0f / fmaxf(sqrtf(kss), 1e-12f);
#pragma unroll
    for (int j = 0; j < 8; j++) {
      qb[ni][j] = (short)f2bf(bf2f((unsigned short)qv[j]) * qinv);
      ka[ni][j] = (short)f2bf(bf2f((unsigned short)kv[j]) * kinv);
    }
  }

  // ---- stage V^T[d][j] (lanes 0..31, in-register 8x8 transpose) ----
  if (lane < 32) {
    int jb = lane >> 2, db = lane & 3;
    short8 rows[8];
#pragma unroll
    for (int r = 0; r < 8; r++) {
      rows[r] =
          *(const short8*)(qkv + (pbase + (size_t)jb * F_W + r) * 768 + hh * 32 + 512 + db * 8);
    }
#pragma unroll
    for (int c = 0; c < 8; c++) {
      int d = db * 8 + c;
      short8 col;
#pragma unroll
      for (int r = 0; r < 8; r++) col[r] = rows[r][c];
      *(short8*)(Vt[wid] + d * 64 + ((jb ^ (d & 7)) * 8)) = col;
    }
  }

  // ---- S^T = K @ Q^T (D[j][i]) ----
  float4v sacc[4][4] = {};
#pragma unroll
  for (int mj = 0; mj < 4; mj++)
#pragma unroll
    for (int ni = 0; ni < 4; ni++)
      sacc[mj][ni] = __builtin_amdgcn_mfma_f32_16x16x32_bf16(ka[mj], qb[ni], sacc[mj][ni], 0, 0, 0);

  float scale = __expf(fminf(logit_scale[hh], 4.605170185988091f));  // ln(100)

  // ---- softmax over j (per col i), write P[i][j] bf16 to LDS ----
#pragma unroll
  for (int ni = 0; ni < 4; ni++) {
    int i = ni * 16 + il;
    const float* rp = rpbt + ((size_t)hh * 64 + i) * 64;
    float sv[16];
    float mx = -1e30f;
#pragma unroll
    for (int mj = 0; mj < 4; mj++) {
      float4 rb = *(const float4*)(rp + mj * 16 + kg * 4);
      float rbs[4] = {rb.x, rb.y, rb.z, rb.w};
#pragma unroll
      for (int r = 0; r < 4; r++) {
        float v = sacc[mj][ni][r] * scale + rbs[r];
        sv[mj * 4 + r] = v;
        mx = fmaxf(mx, v);
      }
    }
    mx = fmaxf(mx, __shfl_xor(mx, 16));
    mx = fmaxf(mx, __shfl_xor(mx, 32));
    float sm = 0.0f;
#pragma unroll
    for (int u = 0; u < 16; u++) {
      sv[u] = __expf(sv[u] - mx);
      sm += sv[u];
    }
    sm += __shfl_xor(sm, 16);
    sm += __shfl_xor(sm, 32);
    float inv = 1.0f / sm;
#pragma unroll
    for (int mj = 0; mj < 4; mj++) {
      int j0 = mj * 16 + kg * 4;
      short4v pk;
#pragma unroll
      for (int r = 0; r < 4; r++) pk[r] = (short)f2bf(sv[mj * 4 + r] * inv);
      int byteoff = i * 128 + (((j0 >> 3) ^ (i & 7)) * 16) + (j0 & 7) * 2;
      *(short4v*)((char*)Pl[wid] + byteoff) = pk;
    }
  }
  __syncthreads();

  // ---- O^T = V^T @ P^T: A = V^T[d][j], B[k=j][n=i] = P[i][j] ----
  float4v oacc[2][4] = {};
#pragma unroll
  for (int kc = 0; kc < 2; kc++) {
    short8 va[2];
#pragma unroll
    for (int md = 0; md < 2; md++) {
      int d = md * 16 + il;
      va[md] = *(const short8*)((char*)Vt[wid] + d * 128 + (((kc * 4 + kg) ^ (d & 7)) * 16));
    }
    short8 pb[4];
#pragma unroll
    for (int ni = 0; ni < 4; ni++) {
      int i = ni * 16 + il;
      pb[ni] = *(const short8*)((char*)Pl[wid] + i * 128 + (((kc * 4 + kg) ^ (i & 7)) * 16));
    }
#pragma unroll
    for (int md = 0; md < 2; md++)
#pragma unroll
      for (int ni = 0; ni < 4; ni++)
        oacc[md][ni] =
            __builtin_amdgcn_mfma_f32_16x16x32_bf16(va[md], pb[ni], oacc[md][ni], 0, 0, 0);
  }

  // ---- write out: O^T col = i = lane&15, row d = md*16 + kg*4 + r ----
#pragma unroll
  for (int ni = 0; ni < 4; ni++) {
    int i = ni * 16 + il;
    size_t orow = (pbase + (size_t)(i >> 3) * F_W + (i & 7)) * 256 + hh * 32;
#pragma unroll
    for (int md = 0; md < 2; md++) {
      int d0 = md * 16 + kg * 4;
      short4v pk;
#pragma unroll
      for (int r = 0; r < 4; r++) pk[r] = (short)f2bf(oacc[md][ni][r]);
      *(short4v*)(out + orow + d0) = pk;
    }
  }
}

// ---------------- launch ----------------
extern "C" void kernel_launch(void* const* d_in, const int* in_sizes, int n_in,
                              void* d_out, int out_size, void* d_ws, size_t ws_size,
                              hipStream_t stream) {
  const float* x = (const float*)d_in[0];
  const float* y = (const float*)d_in[1];
  const float* Wq = (const float*)d_in[2];
  const float* bq = (const float*)d_in[3];
  const float* Wk = (const float*)d_in[4];
  const float* bk = (const float*)d_in[5];
  const float* Wv = (const float*)d_in[6];
  const float* bv = (const float*)d_in[7];
  const float* gamma = (const float*)d_in[8];
  const float* qkv_w = (const float*)d_in[9];
  const float* q_bias = (const float*)d_in[10];
  const float* v_bias = (const float*)d_in[11];
  const float* logit_scale = (const float*)d_in[12];
  const float* cpb_w1 = (const float*)d_in[13];
  const float* cpb_b1 = (const float*)d_in[14];
  const float* cpb_w2 = (const float*)d_in[15];
  const float* proj_w = (const float*)d_in[16];
  const float* proj_b = (const float*)d_in[17];

  float* ws = (float*)d_ws;
  const size_t NPX = (size_t)F_B * F_HW;  // 131072
  const size_t M1 = NPX * 256;            // 33.55M floats (= bf16 plane is M1/2 floats)
  // regions (float offsets). bf16 planes are M1/2 floats each:
  size_t f_xb = 0;                 // xb bf16 [0, M1/2)
  size_t f_ytb = M1 / 2;           // ytb bf16; eb bf16 overlays after v-GEMM
  size_t f_vtb = M1;               // vtb bf16
  size_t f_pob = M1 + M1 / 2;      // pob bf16; attn_b bf16 overlays after pv
  size_t f_ccb = 2 * M1;           // ccb bf16
  size_t f_qkb = 2 * M1 + M1 / 2;  // qkb fp32 (NPX*64)
  // qkvb bf16 (1.5*M1 floats) overlays [0, 1.5*M1) after pv<1> (xb/eb/vtb dead)
  size_t f_wts = f_qkb + NPX * 64;
  size_t o_qkwb = f_wts;              // 16384 ushort -> 8192 f
  size_t o_Wvb = o_qkwb + 8192;       // 65536 ushort -> 32768 f
  size_t o_qkvwb = o_Wvb + 32768;     // 196608 ushort -> 98304 f
  size_t o_projwb = o_qkvwb + 98304;  // 65536 ushort -> 32768 f
  size_t o_qkb2 = o_projwb + 32768;   // 64 f
  size_t o_qkvb2 = o_qkb2 + 64;       // 768 f
  size_t o_tbl = o_qkvb2 + 768;       // 1800 f
  size_t o_sumH = o_tbl + 1800;       // NPX f
  size_t o_sumW = o_sumH + NPX;       // NPX f
  size_t o_rpbt = o_sumW + NPX;       // 32768 f
  size_t need = (o_rpbt + 32768) * sizeof(float);
  if (ws_size < need) {
    fprintf(stderr, "kernel_launch: ws too small: %zu < %zu\n", ws_size, need);
    return;
  }
  unsigned short* xb = (unsigned short*)(ws + f_xb);
  unsigned short* qkvb = (unsigned short*)(ws + f_xb);  // overlays [0, 1.5*M1)
  unsigned short* ytb = (unsigned short*)(ws + f_ytb);
  unsigned short* eb = (unsigned short*)(ws + f_ytb);
  unsigned short* vtb = (unsigned short*)(ws + f_vtb);
  unsigned short* pob = (unsigned short*)(ws + f_pob);
  unsigned short* attn_b = (unsigned short*)(ws + f_pob);
  unsigned short* ccb = (unsigned short*)(ws + f_ccb);
  float* qkb = ws + f_qkb;
  unsigned short* qk_wb = (unsigned short*)(ws + o_qkwb);
  unsigned short* Wvb = (unsigned short*)(ws + o_Wvb);
  unsigned short* qkv_wb = (unsigned short*)(ws + o_qkvwb);
  unsigned short* proj_wb = (unsigned short*)(ws + o_projwb);
  float* qk_b = ws + o_qkb2;
  float* qkv_b = ws + o_qkvb2;
  float* tblS = ws + o_tbl;
  float* sumH = ws + o_sumH;
  float* sumW = ws + o_sumW;
  float* rpbt = ws + o_rpbt;

  build_aux2<<<dim3(768), dim3(256), 0, stream>>>(Wq, Wk, bq, bk, q_bias, v_bias, Wv, qkv_w,
                                                  proj_w, qk_wb, qk_b, qkv_b, Wvb, qkv_wb,
                                                  proj_wb);
  cpb_table<<<dim3(225), dim3(256), 0, stream>>>(cpb_w1, cpb_b1, cpb_w2, tblS);
  build_rpbt<<<dim3(128), dim3(256), 0, stream>>>(tblS, rpbt);
  // x^T -> xb bf16 ; y^T -> ytb bf16
  transpose_bf<<<dim3(512, 8, 8), dim3(256), 0, stream>>>(x, xb);
  transpose_bf<<<dim3(512, 8, 8), dim3(256), 0, stream>>>(y, ytb);
  // q|k projection: (BHW x 256) @ (64 x 256)^T -> fp32
  gemm_mfma<64, 0><<<dim3(1024), dim3(256), 0, stream>>>(xb, qk_wb, qk_b, qkb, (int)NPX, 64,
                                                         1);
  // v projection -> bf16 vtb
  gemm_mfma<128, 2><<<dim3(2048), dim3(256), 0, stream>>>(ytb, Wvb, bv, vtb, (int)NPX, 256, 2);
  // criss-cross attention (GEMM-structured, bf16 e, fused partial sums)
  cc_logits<0><<<dim3(128, 8), dim3(256), 0, stream>>>(qkb, eb, sumH);
  cc_logits<1><<<dim3(128, 8), dim3(256), 0, stream>>>(qkb, eb, sumW);
  cc_pv_mfma<0><<<dim3(128, 8), dim3(256), 0, stream>>>(eb, vtb, sumH, sumW, gamma, xb, pob,
                                                        ccb);
  cc_pv_mfma<1><<<dim3(128, 8), dim3(256), 0, stream>>>(eb, vtb, sumH, sumW, gamma, xb, pob,
                                                        ccb);
  // window qkv projection (full, bf16) + window attention (MFMA)
  gemm_mfma<128, 2><<<dim3(6144), dim3(256), 0, stream>>>(ccb, qkv_wb, qkv_b, qkvb, (int)NPX,
                                                          768, 6);
  win_attn_mfma<<<dim3(2048, 2), dim3(256), 0, stream>>>(qkvb, logit_scale, rpbt, attn_b);
  // output projection with transposed (B,C,H,W) write
  gemm_mfma<128, 1><<<dim3(2048), dim3(256), 0, stream>>>(attn_b, proj_wb, proj_b, d_out,
                                                          (int)NPX, 256, 2);
}

// Round 10
// 635.657 us; speedup vs baseline: 1.0297x; 1.0297x over previous
//
#include <hip/hip_runtime.h>
#include <cstdio>
#include <cstddef>
#include <cstdint>

#define F_B 8
#define F_C 256
#define F_H 128
#define F_W 128
#define F_HW 16384

typedef __attribute__((ext_vector_type(8))) short short8;   // bf16x8 MFMA operand
typedef __attribute__((ext_vector_type(4))) short short4v;  // bf16x4
typedef __attribute__((ext_vector_type(4))) float float4v;  // MFMA accumulator

__device__ __forceinline__ unsigned short f2bf(float f) {
  union {
    float f;
    uint32_t u;
  } v;
  v.f = f;
  return (unsigned short)((v.u + 0x7fffu + ((v.u >> 16) & 1u)) >> 16);
}

__device__ __forceinline__ float bf2f(unsigned short u) {
  union {
    uint32_t u;
    float f;
  } v;
  v.u = ((uint32_t)u) << 16;
  return v.f;
}

__device__ __forceinline__ void async_copy16(const unsigned short* g, unsigned short* l) {
  __builtin_amdgcn_global_load_lds((const __attribute__((address_space(1))) void*)g,
                                   (__attribute__((address_space(3))) void*)l, 16, 0, 0);
}

// ---------------- aux: weight bf16 conversion + bias concat ----------------
__global__ void build_aux2(const float* __restrict__ Wq, const float* __restrict__ Wk,
                           const float* __restrict__ bq, const float* __restrict__ bk,
                           const float* __restrict__ q_bias, const float* __restrict__ v_bias,
                           const float* __restrict__ Wv, const float* __restrict__ qkv_w,
                           const float* __restrict__ proj_w, unsigned short* __restrict__ qk_wb,
                           float* __restrict__ qk_b, float* __restrict__ qkv_b,
                           unsigned short* __restrict__ Wvb, unsigned short* __restrict__ qkv_wb,
                           unsigned short* __restrict__ proj_wb) {
  int t = blockIdx.x * 256 + threadIdx.x;  // 768 blocks -> 196608 threads
  if (t < 8192) {
    qk_wb[t] = f2bf(Wq[t]);
    qk_wb[8192 + t] = f2bf(Wk[t]);
  }
  if (t < 65536) {
    Wvb[t] = f2bf(Wv[t]);
    proj_wb[t] = f2bf(proj_w[t]);
  }
  if (t < 196608) qkv_wb[t] = f2bf(qkv_w[t]);
  if (t < 32) {
    qk_b[t] = bq[t];
    qk_b[32 + t] = bk[t];
  }
  if (t < 256) {
    qkv_b[t] = q_bias[t];
    qkv_b[256 + t] = 0.0f;
    qkv_b[512 + t] = v_bias[t];
  }
}

// ---------------- CPB MLP table: tblS[225][8] = 16*sigmoid(mlp(coords)) -----
__device__ __forceinline__ float cpb_coord(int a) {
  float v = (float)(a - 7) * (8.0f / 7.0f);
  float lg = log2f(fabsf(v) + 1.0f) * (1.0f / 3.0f);  // /log2(8)
  return (v < 0.0f) ? -lg : lg;
}

__global__ void cpb_table(const float* __restrict__ w1, const float* __restrict__ b1,
                          const float* __restrict__ w2, float* __restrict__ tblS) {
  int e = blockIdx.x;  // 0..224
  int yi = e / 15, xi = e % 15;
  float ry = cpb_coord(yi), rx = cpb_coord(xi);
  __shared__ float hid[512];
  int t = threadIdx.x;  // 256
  for (int j = t; j < 512; j += 256) {
    float hv = w1[j * 2] * ry + w1[j * 2 + 1] * rx + b1[j];
    hid[j] = fmaxf(hv, 0.0f);
  }
  __syncthreads();
  if (t < 8) {
    float s = 0.0f;
    for (int j = 0; j < 512; j++) s += hid[j] * w2[t * 512 + j];
    tblS[e * 8 + t] = 16.0f / (1.0f + __expf(-s));
  }
}

// ---------------- rpbt[h][i][j] = tblS[e(i,j)*8+h]  (window-independent) ----
__global__ void build_rpbt(const float* __restrict__ tblS, float* __restrict__ rpbt) {
  int t = blockIdx.x * 256 + threadIdx.x;  // < 32768
  int h = t >> 12, i = (t >> 6) & 63, j = t & 63;
  int e = ((i >> 3) - (j >> 3) + 7) * 15 + ((i & 7) - (j & 7) + 7);
  rpbt[t] = tblS[e * 8 + h];
}

// ---------------- transpose (B,C,HW) -> (B,HW,C) bf16, short4 stores -------
__global__ void transpose_bf(const float* __restrict__ in, unsigned short* __restrict__ outb) {
  __shared__ float tile[32][33];
  int b = blockIdx.z;
  int p0 = blockIdx.x * 32;
  int c0 = blockIdx.y * 32;
  const float* src = in + (size_t)b * F_C * F_HW;
  int t = threadIdx.x;
  int tx = t & 31, ty = t >> 5;  // tx = pixel, ty = channel-base (8)
#pragma unroll
  for (int i = 0; i < 4; i++) {
    tile[ty + i * 8][tx] = src[(size_t)(c0 + ty + i * 8) * F_HW + p0 + tx];
  }
  __syncthreads();
  int pix = t >> 3, cl = (t & 7) * 4;
  short4v pk;
#pragma unroll
  for (int u = 0; u < 4; u++) pk[u] = (short)f2bf(tile[cl + u][pix]);
  size_t idx = (size_t)b * F_HW * F_C + (size_t)(p0 + pix) * F_C + c0 + cl;
  *(short4v*)(outb + idx) = pk;
}

// ---------------- bf16 MFMA GEMM: C[M,N] = A[M,256] @ W[N,256]^T + bias ----
// 1-D grid, XCD-chunked swizzle. DOUBLE-BUFFERED LDS (2-phase pipeline):
// per K-iter: issue next tile's global_load_lds into buf^1 FIRST, then
// ds_read+MFMA from buf, then one barrier — the prefetch latency hides under
// the MFMAs instead of being serialized behind its own barrier.
// Swizzle f(r)=(r>>1)&3 on both sides (conflict-free, round-8-verified).
// OUT 0: fp32 row-major. OUT 1: fp32 out[((row>>14)*N+col)*16384+(row&16383)].
// OUT 2: bf16 row-major.
template <int BN, int OUT>
__global__ __launch_bounds__(256) void gemm_mfma(const unsigned short* __restrict__ A,
                                                 const unsigned short* __restrict__ Wt,
                                                 const float* __restrict__ bias, void* Cmat,
                                                 int M, int N, int gx) {
  constexpr int WN = BN / 2;
  constexpr int NREP = WN / 16;
  __shared__ __align__(16) unsigned short As[2][128 * 32];
  __shared__ __align__(16) unsigned short Bs[2][BN * 32];
  int nwg = gridDim.x;
  int id = blockIdx.x;
  int cpx = nwg >> 3;
  int swz = (id & 7) * cpx + (id >> 3);
  int by = swz / gx;
  int bx = swz - by * gx;
  int m0 = by * 128;
  int n0 = bx * BN;
  int t = threadIdx.x;
  int wid = t >> 6, lane = t & 63;
  int wr = wid >> 1, wc = wid & 1;

  // staging addresses ((r>>1)&3 is invariant under +16/+32 row offsets)
  int rA = wid * 32 + (lane >> 2);
  int kgA = (lane & 3) ^ ((rA >> 1) & 3);
  const unsigned short* gpA = A + (size_t)(m0 + rA) * 256 + kgA * 8;
  int rB = wid * (BN / 4) + (lane >> 2);
  int kgB = (lane & 3) ^ ((rB >> 1) & 3);
  const unsigned short* gpB = Wt + (size_t)(n0 + rB) * 256 + kgB * 8;

  auto STAGE = [&](int buf, int k0) {
#pragma unroll
    for (int j = 0; j < 2; j++)
      async_copy16(gpA + (size_t)j * 16 * 256 + k0, &As[buf][(wid * 32 + j * 16) * 32]);
#pragma unroll
    for (int j = 0; j < BN / 64; j++)
      async_copy16(gpB + (size_t)j * 16 * 256 + k0,
                   &Bs[buf][(wid * (BN / 4) + j * 16) * 32]);
  };

  float4v acc[4][NREP] = {};

  STAGE(0, 0);
  __syncthreads();
  int cur = 0;
  for (int k0 = 0; k0 < 256; k0 += 32) {
    if (k0 < 224) STAGE(cur ^ 1, k0 + 32);
    short8 af[4];
#pragma unroll
    for (int mi = 0; mi < 4; mi++) {
      int row = wr * 64 + mi * 16 + (lane & 15);
      int kg = (lane >> 4) ^ ((row >> 1) & 3);
      af[mi] = *(const short8*)(&As[cur][row * 32 + kg * 8]);
    }
    short8 bfr[NREP];
#pragma unroll
    for (int ni = 0; ni < NREP; ni++) {
      int col = wc * WN + ni * 16 + (lane & 15);
      int kg = (lane >> 4) ^ ((col >> 1) & 3);
      bfr[ni] = *(const short8*)(&Bs[cur][col * 32 + kg * 8]);
    }
#pragma unroll
    for (int mi = 0; mi < 4; mi++)
#pragma unroll
      for (int ni = 0; ni < NREP; ni++)
        acc[mi][ni] =
            __builtin_amdgcn_mfma_f32_16x16x32_bf16(af[mi], bfr[ni], acc[mi][ni], 0, 0, 0);
    __syncthreads();
    cur ^= 1;
  }
#pragma unroll
  for (int ni = 0; ni < NREP; ni++) {
    int col = n0 + wc * WN + ni * 16 + (lane & 15);
    float bn = bias[col];
#pragma unroll
    for (int mi = 0; mi < 4; mi++) {
      int row0 = m0 + wr * 64 + mi * 16 + (lane >> 4) * 4;
      if (OUT == 1) {
        float4 st;
        st.x = acc[mi][ni][0] + bn;
        st.y = acc[mi][ni][1] + bn;
        st.z = acc[mi][ni][2] + bn;
        st.w = acc[mi][ni][3] + bn;
        int bb = row0 >> 14, p = row0 & 16383;
        *(float4*)((float*)Cmat + ((size_t)bb * N + col) * F_HW + p) = st;
      } else {
#pragma unroll
        for (int r = 0; r < 4; r++) {
          float v = acc[mi][ni][r] + bn;
          int row = row0 + r;
          if (OUT == 0)
            ((float*)Cmat)[(size_t)row * N + col] = v;
          else
            ((unsigned short*)Cmat)[(size_t)row * N + col] = f2bf(v);
        }
      }
    }
  }
}

// ---------------- criss-cross logits (bf16 exp output + partial row sum) ----
// MODE 0 (H/column): block (w=x, b); E[h,g] = q(h,x)·k(g,x); e[pix(h,x)][g], diag->0
// MODE 1 (W/row):    block (h=x, b); E[w,v] = q(x,w)·k(x,v); e[pix(x,w)][128+v]
// sums[pix] = sum over this mode's 128 exps.
template <int MODE>
__global__ __launch_bounds__(256) void cc_logits(const float* __restrict__ qk,
                                                 unsigned short* __restrict__ e,
                                                 float* __restrict__ sums) {
  int x = blockIdx.x;
  int b = blockIdx.y;
  size_t base = (size_t)b * F_HW;
  __shared__ float kt[32][132];  // kt[c][g]
  int t = threadIdx.x;
  {
    int gk = t >> 1, c0 = (t & 1) * 16;
    size_t krow = (MODE == 0) ? ((size_t)gk * F_W + x) : ((size_t)x * F_W + gk);
    const float4* src = (const float4*)(qk + (base + krow) * 64 + 32 + c0);
#pragma unroll
    for (int q4 = 0; q4 < 4; q4++) {
      float4 v = src[q4];
      kt[c0 + q4 * 4 + 0][gk] = v.x;
      kt[c0 + q4 * 4 + 1][gk] = v.y;
      kt[c0 + q4 * 4 + 2][gk] = v.z;
      kt[c0 + q4 * 4 + 3][gk] = v.w;
    }
  }
  __syncthreads();
  int i = t >> 1, g0 = (t & 1) * 64;
  size_t qrow = (MODE == 0) ? ((size_t)i * F_W + x) : ((size_t)x * F_W + i);
  const float4* qp = (const float4*)(qk + (base + qrow) * 64);
  float qreg[32];
#pragma unroll
  for (int q4 = 0; q4 < 8; q4++) {
    float4 v = qp[q4];
    qreg[q4 * 4 + 0] = v.x;
    qreg[q4 * 4 + 1] = v.y;
    qreg[q4 * 4 + 2] = v.z;
    qreg[q4 * 4 + 3] = v.w;
  }
  float acc[64];
#pragma unroll
  for (int g = 0; g < 64; g++) acc[g] = 0.0f;
  for (int c = 0; c < 32; c++) {
    float qv = qreg[c];
#pragma unroll
    for (int g = 0; g < 64; g++) acc[g] += qv * kt[c][g0 + g];
  }
  if (MODE == 0) {
    int d = i - g0;
    if (d >= 0 && d < 64) acc[d] = -1e9f;  // diag mask -> exp = 0
  }
  unsigned short* ep = e + (base + qrow) * 256 + MODE * 128 + g0;
  float s = 0.0f;
#pragma unroll
  for (int g = 0; g < 64; g += 8) {
    short8 pk;
#pragma unroll
    for (int j = 0; j < 8; j++) {
      float ev = __expf(acc[g + j]);
      s += ev;
      pk[j] = (short)f2bf(ev);
    }
    *(short8*)(ep + g) = pk;
  }
  s += __shfl_xor(s, 1);  // pair (t, t^1) share the same row i
  if ((t & 1) == 0) sums[base + qrow] = s;
}

// ---------------- criss-cross PV, bf16 MFMA (swapped operands) ----------------
// O[i][c] = sum_k Anorm[i][k] * V[k][c] per (x,b) block; 128x256x128.
// Swapped MFMA: lane holds fixed i, 4 consecutive c -> 8B loads/stores.
// MODE 0: i=h (col x fixed), k=g, pix(i)=i*128+x  -> writes pob = bf16 raw oH
// MODE 1: i=w (row x fixed), k=v, pix(i)=x*128+i  -> ccb = bf16(gm*(po+oW)+x)
template <int MODE>
__global__ __launch_bounds__(256) void cc_pv_mfma(const unsigned short* __restrict__ eb,
                                                  const unsigned short* __restrict__ vtb,
                                                  const float* __restrict__ sumH,
                                                  const float* __restrict__ sumW,
                                                  const float* __restrict__ gamma,
                                                  const unsigned short* __restrict__ xb,
                                                  unsigned short* __restrict__ pob,
                                                  unsigned short* __restrict__ ccb) {
  int x = blockIdx.x, b = blockIdx.y;
  size_t base = (size_t)b * F_HW;
  __shared__ __align__(16) unsigned short As[128 * 128];  // [i][k], swizzled, 32 KB
  __shared__ __align__(16) unsigned short Vs[256 * 64];   // [c][k-chunk], swizzled, 32 KB
  int t = threadIdx.x;
  int wid = t >> 6, lane = t & 63;
  int wr = wid >> 1, wc = wid & 1;
  // ---- stage A = normalized e (bf16) ----
  {
    int i = t >> 1, half = t & 1;
    size_t pix = (MODE == 0) ? ((size_t)i * F_W + x) : ((size_t)x * F_W + i);
    float rv = 1.0f / (sumH[base + pix] + sumW[base + pix]);
    const unsigned short* ep = eb + (base + pix) * 256 + MODE * 128 + half * 64;
    int g = ((i >> 3) & 7) ^ (i & 7);
#pragma unroll
    for (int s = 0; s < 8; s++) {
      short8 vin = *(const short8*)(ep + s * 8);
      short8 vo;
#pragma unroll
      for (int j = 0; j < 8; j++) vo[j] = (short)f2bf(bf2f((unsigned short)vin[j]) * rv);
      int slot = (half * 8 + s) ^ g;  // g is 3-bit: half bit preserved
      *(short8*)(As + i * 128 + slot * 8) = vo;
    }
  }
  float4v acc[4][8] = {};
#pragma unroll
  for (int kc = 0; kc < 2; kc++) {
    __syncthreads();
    // ---- stage Vs[c][k] for k-chunk kc: in-register 8x8 transpose ----
    {
      int ko = t >> 5, cj = t & 31;
      short8 rowv[8];
#pragma unroll
      for (int r = 0; r < 8; r++) {
        int kk = kc * 64 + ko * 8 + r;
        size_t pixk = (MODE == 0) ? ((size_t)kk * F_W + x) : ((size_t)x * F_W + kk);
        rowv[r] = *(const short8*)(vtb + (base + pixk) * 256 + cj * 8);
      }
#pragma unroll
      for (int j = 0; j < 8; j++) {
        short8 col;
#pragma unroll
        for (int r = 0; r < 8; r++) col[r] = rowv[r][j];
        int c = cj * 8 + j;
        int slot = ko ^ ((c >> 3) & 7) ^ (c & 7);
        *(short8*)(Vs + c * 64 + slot * 8) = col;
      }
    }
    __syncthreads();
#pragma unroll
    for (int ksub = 0; ksub < 2; ksub++) {
      short8 af[4];
#pragma unroll
      for (int mi = 0; mi < 4; mi++) {
        int i = wr * 64 + mi * 16 + (lane & 15);
        int slot = (kc * 8 + ksub * 4 + (lane >> 4)) ^ ((i >> 3) & 7) ^ (i & 7);
        af[mi] = *(const short8*)(As + i * 128 + slot * 8);
      }
      short8 bfv[8];
#pragma unroll
      for (int ni = 0; ni < 8; ni++) {
        int c = wc * 128 + ni * 16 + (lane & 15);
        int slot = (ksub * 4 + (lane >> 4)) ^ ((c >> 3) & 7) ^ (c & 7);
        bfv[ni] = *(const short8*)(Vs + c * 64 + slot * 8);
      }
#pragma unroll
      for (int mi = 0; mi < 4; mi++)
#pragma unroll
        for (int ni = 0; ni < 8; ni++)
          acc[mi][ni] =
              __builtin_amdgcn_mfma_f32_16x16x32_bf16(bfv[ni], af[mi], acc[mi][ni], 0, 0, 0);
    }
  }
  // ---- epilogue: lane holds fixed i, 4 consecutive c ----
  float gm = gamma[0];
#pragma unroll
  for (int mi = 0; mi < 4; mi++) {
    int i = wr * 64 + mi * 16 + (lane & 15);
    size_t pix = (MODE == 0) ? ((size_t)i * F_W + x) : ((size_t)x * F_W + i);
    size_t rowb = (base + pix) * 256;
#pragma unroll
    for (int ni = 0; ni < 8; ni++) {
      int c0 = wc * 128 + ni * 16 + (lane >> 4) * 4;
      if (MODE == 0) {
        short4v pk;
#pragma unroll
        for (int r = 0; r < 4; r++) pk[r] = (short)f2bf(acc[mi][ni][r]);
        *(short4v*)(pob + rowb + c0) = pk;
      } else {
        short4v po4 = *(const short4v*)(pob + rowb + c0);
        short4v xb4 = *(const short4v*)(xb + rowb + c0);
        short4v pk;
#pragma unroll
        for (int r = 0; r < 4; r++)
          pk[r] = (short)f2bf(gm * (bf2f((unsigned short)po4[r]) + acc[mi][ni][r]) +
                              bf2f((unsigned short)xb4[r]));
        *(short4v*)(ccb + rowb + c0) = pk;
      }
    }
  }
}

// ---------------- window attention, MFMA: 1 wave per (window, head) --------
// qkv: [NPX][768] bf16 (q|k|v, head-major 32). out: [NPX][256] bf16.
// rpbt: [8][64][64] fp32 = 16*sigmoid(cpb) per (head, i, j).
__global__ __launch_bounds__(256) void win_attn_mfma(const unsigned short* __restrict__ qkv,
                                                     const float* __restrict__ logit_scale,
                                                     const float* __restrict__ rpbt,
                                                     unsigned short* __restrict__ out) {
  __shared__ __align__(16) unsigned short Pl[4][4096];  // per-wave P[i][j] bf16, swizzled
  __shared__ __align__(16) unsigned short Vt[4][2048];  // per-wave V^T[d][j] bf16, swizzled
  int win = blockIdx.x;
  int wid = threadIdx.x >> 6, lane = threadIdx.x & 63;
  int hh = blockIdx.y * 4 + wid;
  int b = win >> 8, wy = (win >> 4) & 15, wx = win & 15;
  size_t pbase = (size_t)b * F_HW + (size_t)(wy * 8) * F_W + wx * 8;
  int il = lane & 15, kg = lane >> 4;

  // ---- load + cosine-normalize Q (B-frags) and K (A-frags) ----
  short8 qb[4], ka[4];
#pragma unroll
  for (int ni = 0; ni < 4; ni++) {
    int i = ni * 16 + il;
    size_t row = (pbase + (size_t)(i >> 3) * F_W + (i & 7)) * 768 + hh * 32 + kg * 8;
    short8 qv = *(const short8*)(qkv + row);
    short8 kv = *(const short8*)(qkv + row + 256);
    float qss = 0.0f, kss = 0.0f;
#pragma unroll
    for (int j = 0; j < 8; j++) {
      float qf = bf2f((unsigned short)qv[j]);
      float kf = bf2f((unsigned short)kv[j]);
      qss += qf * qf;
      kss += kf * kf;
    }
    qss += __shfl_xor(qss, 16);
    qss += __shfl_xor(qss, 32);
    kss += __shfl_xor(kss, 16);
    kss += __shfl_xor(kss, 32);
    float qinv = 1.0f / fmaxf(sqrtf(qss), 1e-12f);
    float kinv = 1.0f / fmaxf(sqrtf(kss), 1e-12f);
#pragma unroll
    for (int j = 0; j < 8; j++) {
      qb[ni][j] = (short)f2bf(bf2f((unsigned short)qv[j]) * qinv);
      ka[ni][j] = (short)f2bf(bf2f((unsigned short)kv[j]) * kinv);
    }
  }

  // ---- stage V^T[d][j] (lanes 0..31, in-register 8x8 transpose) ----
  if (lane < 32) {
    int jb = lane >> 2, db = lane & 3;
    short8 rows[8];
#pragma unroll
    for (int r = 0; r < 8; r++) {
      rows[r] =
          *(const short8*)(qkv + (pbase + (size_t)jb * F_W + r) * 768 + hh * 32 + 512 + db * 8);
    }
#pragma unroll
    for (int c = 0; c < 8; c++) {
      int d = db * 8 + c;
      short8 col;
#pragma unroll
      for (int r = 0; r < 8; r++) col[r] = rows[r][c];
      *(short8*)(Vt[wid] + d * 64 + ((jb ^ (d & 7)) * 8)) = col;
    }
  }

  // ---- S^T = K @ Q^T (D[j][i]) ----
  float4v sacc[4][4] = {};
#pragma unroll
  for (int mj = 0; mj < 4; mj++)
#pragma unroll
    for (int ni = 0; ni < 4; ni++)
      sacc[mj][ni] = __builtin_amdgcn_mfma_f32_16x16x32_bf16(ka[mj], qb[ni], sacc[mj][ni], 0, 0, 0);

  float scale = __expf(fminf(logit_scale[hh], 4.605170185988091f));  // ln(100)

  // ---- softmax over j (per col i), write P[i][j] bf16 to LDS ----
#pragma unroll
  for (int ni = 0; ni < 4; ni++) {
    int i = ni * 16 + il;
    const float* rp = rpbt + ((size_t)hh * 64 + i) * 64;
    float sv[16];
    float mx = -1e30f;
#pragma unroll
    for (int mj = 0; mj < 4; mj++) {
      float4 rb = *(const float4*)(rp + mj * 16 + kg * 4);
      float rbs[4] = {rb.x, rb.y, rb.z, rb.w};
#pragma unroll
      for (int r = 0; r < 4; r++) {
        float v = sacc[mj][ni][r] * scale + rbs[r];
        sv[mj * 4 + r] = v;
        mx = fmaxf(mx, v);
      }
    }
    mx = fmaxf(mx, __shfl_xor(mx, 16));
    mx = fmaxf(mx, __shfl_xor(mx, 32));
    float sm = 0.0f;
#pragma unroll
    for (int u = 0; u < 16; u++) {
      sv[u] = __expf(sv[u] - mx);
      sm += sv[u];
    }
    sm += __shfl_xor(sm, 16);
    sm += __shfl_xor(sm, 32);
    float inv = 1.0f / sm;
#pragma unroll
    for (int mj = 0; mj < 4; mj++) {
      int j0 = mj * 16 + kg * 4;
      short4v pk;
#pragma unroll
      for (int r = 0; r < 4; r++) pk[r] = (short)f2bf(sv[mj * 4 + r] * inv);
      int byteoff = i * 128 + (((j0 >> 3) ^ (i & 7)) * 16) + (j0 & 7) * 2;
      *(short4v*)((char*)Pl[wid] + byteoff) = pk;
    }
  }
  __syncthreads();

  // ---- O^T = V^T @ P^T: A = V^T[d][j], B[k=j][n=i] = P[i][j] ----
  float4v oacc[2][4] = {};
#pragma unroll
  for (int kc = 0; kc < 2; kc++) {
    short8 va[2];
#pragma unroll
    for (int md = 0; md < 2; md++) {
      int d = md * 16 + il;
      va[md] = *(const short8*)((char*)Vt[wid] + d * 128 + (((kc * 4 + kg) ^ (d & 7)) * 16));
    }
    short8 pb[4];
#pragma unroll
    for (int ni = 0; ni < 4; ni++) {
      int i = ni * 16 + il;
      pb[ni] = *(const short8*)((char*)Pl[wid] + i * 128 + (((kc * 4 + kg) ^ (i & 7)) * 16));
    }
#pragma unroll
    for (int md = 0; md < 2; md++)
#pragma unroll
      for (int ni = 0; ni < 4; ni++)
        oacc[md][ni] =
            __builtin_amdgcn_mfma_f32_16x16x32_bf16(va[md], pb[ni], oacc[md][ni], 0, 0, 0);
  }

  // ---- write out: O^T col = i = lane&15, row d = md*16 + kg*4 + r ----
#pragma unroll
  for (int ni = 0; ni < 4; ni++) {
    int i = ni * 16 + il;
    size_t orow = (pbase + (size_t)(i >> 3) * F_W + (i & 7)) * 256 + hh * 32;
#pragma unroll
    for (int md = 0; md < 2; md++) {
      int d0 = md * 16 + kg * 4;
      short4v pk;
#pragma unroll
      for (int r = 0; r < 4; r++) pk[r] = (short)f2bf(oacc[md][ni][r]);
      *(short4v*)(out + orow + d0) = pk;
    }
  }
}

// ---------------- launch ----------------
extern "C" void kernel_launch(void* const* d_in, const int* in_sizes, int n_in,
                              void* d_out, int out_size, void* d_ws, size_t ws_size,
                              hipStream_t stream) {
  const float* x = (const float*)d_in[0];
  const float* y = (const float*)d_in[1];
  const float* Wq = (const float*)d_in[2];
  const float* bq = (const float*)d_in[3];
  const float* Wk = (const float*)d_in[4];
  const float* bk = (const float*)d_in[5];
  const float* Wv = (const float*)d_in[6];
  const float* bv = (const float*)d_in[7];
  const float* gamma = (const float*)d_in[8];
  const float* qkv_w = (const float*)d_in[9];
  const float* q_bias = (const float*)d_in[10];
  const float* v_bias = (const float*)d_in[11];
  const float* logit_scale = (const float*)d_in[12];
  const float* cpb_w1 = (const float*)d_in[13];
  const float* cpb_b1 = (const float*)d_in[14];
  const float* cpb_w2 = (const float*)d_in[15];
  const float* proj_w = (const float*)d_in[16];
  const float* proj_b = (const float*)d_in[17];

  float* ws = (float*)d_ws;
  const size_t NPX = (size_t)F_B * F_HW;  // 131072
  const size_t M1 = NPX * 256;            // 33.55M floats (= bf16 plane is M1/2 floats)
  // regions (float offsets). bf16 planes are M1/2 floats each:
  size_t f_xb = 0;                 // xb bf16 [0, M1/2)
  size_t f_ytb = M1 / 2;           // ytb bf16; eb bf16 overlays after v-GEMM
  size_t f_vtb = M1;               // vtb bf16
  size_t f_pob = M1 + M1 / 2;      // pob bf16; attn_b bf16 overlays after pv
  size_t f_ccb = 2 * M1;           // ccb bf16
  size_t f_qkb = 2 * M1 + M1 / 2;  // qkb fp32 (NPX*64)
  // qkvb bf16 (1.5*M1 floats) overlays [0, 1.5*M1) after pv<1> (xb/eb/vtb dead)
  size_t f_wts = f_qkb + NPX * 64;
  size_t o_qkwb = f_wts;              // 16384 ushort -> 8192 f
  size_t o_Wvb = o_qkwb + 8192;       // 65536 ushort -> 32768 f
  size_t o_qkvwb = o_Wvb + 32768;     // 196608 ushort -> 98304 f
  size_t o_projwb = o_qkvwb + 98304;  // 65536 ushort -> 32768 f
  size_t o_qkb2 = o_projwb + 32768;   // 64 f
  size_t o_qkvb2 = o_qkb2 + 64;       // 768 f
  size_t o_tbl = o_qkvb2 + 768;       // 1800 f
  size_t o_sumH = o_tbl + 1800;       // NPX f
  size_t o_sumW = o_sumH + NPX;       // NPX f
  size_t o_rpbt = o_sumW + NPX;       // 32768 f
  size_t need = (o_rpbt + 32768) * sizeof(float);
  if (ws_size < need) {
    fprintf(stderr, "kernel_launch: ws too small: %zu < %zu\n", ws_size, need);
    return;
  }
  unsigned short* xb = (unsigned short*)(ws + f_xb);
  unsigned short* qkvb = (unsigned short*)(ws + f_xb);  // overlays [0, 1.5*M1)
  unsigned short* ytb = (unsigned short*)(ws + f_ytb);
  unsigned short* eb = (unsigned short*)(ws + f_ytb);
  unsigned short* vtb = (unsigned short*)(ws + f_vtb);
  unsigned short* pob = (unsigned short*)(ws + f_pob);
  unsigned short* attn_b = (unsigned short*)(ws + f_pob);
  unsigned short* ccb = (unsigned short*)(ws + f_ccb);
  float* qkb = ws + f_qkb;
  unsigned short* qk_wb = (unsigned short*)(ws + o_qkwb);
  unsigned short* Wvb = (unsigned short*)(ws + o_Wvb);
  unsigned short* qkv_wb = (unsigned short*)(ws + o_qkvwb);
  unsigned short* proj_wb = (unsigned short*)(ws + o_projwb);
  float* qk_b = ws + o_qkb2;
  float* qkv_b = ws + o_qkvb2;
  float* tblS = ws + o_tbl;
  float* sumH = ws + o_sumH;
  float* sumW = ws + o_sumW;
  float* rpbt = ws + o_rpbt;

  build_aux2<<<dim3(768), dim3(256), 0, stream>>>(Wq, Wk, bq, bk, q_bias, v_bias, Wv, qkv_w,
                                                  proj_w, qk_wb, qk_b, qkv_b, Wvb, qkv_wb,
                                                  proj_wb);
  cpb_table<<<dim3(225), dim3(256), 0, stream>>>(cpb_w1, cpb_b1, cpb_w2, tblS);
  build_rpbt<<<dim3(128), dim3(256), 0, stream>>>(tblS, rpbt);
  // x^T -> xb bf16 ; y^T -> ytb bf16
  transpose_bf<<<dim3(512, 8, 8), dim3(256), 0, stream>>>(x, xb);
  transpose_bf<<<dim3(512, 8, 8), dim3(256), 0, stream>>>(y, ytb);
  // q|k projection: (BHW x 256) @ (64 x 256)^T -> fp32
  gemm_mfma<64, 0><<<dim3(1024), dim3(256), 0, stream>>>(xb, qk_wb, qk_b, qkb, (int)NPX, 64,
                                                         1);
  // v projection -> bf16 vtb
  gemm_mfma<128, 2><<<dim3(2048), dim3(256), 0, stream>>>(ytb, Wvb, bv, vtb, (int)NPX, 256, 2);
  // criss-cross attention (GEMM-structured, bf16 e, fused partial sums)
  cc_logits<0><<<dim3(128, 8), dim3(256), 0, stream>>>(qkb, eb, sumH);
  cc_logits<1><<<dim3(128, 8), dim3(256), 0, stream>>>(qkb, eb, sumW);
  cc_pv_mfma<0><<<dim3(128, 8), dim3(256), 0, stream>>>(eb, vtb, sumH, sumW, gamma, xb, pob,
                                                        ccb);
  cc_pv_mfma<1><<<dim3(128, 8), dim3(256), 0, stream>>>(eb, vtb, sumH, sumW, gamma, xb, pob,
                                                        ccb);
  // window qkv projection (full, bf16) + window attention (MFMA)
  gemm_mfma<128, 2><<<dim3(6144), dim3(256), 0, stream>>>(ccb, qkv_wb, qkv_b, qkvb, (int)NPX,
                                                          768, 6);
  win_attn_mfma<<<dim3(2048, 2), dim3(256), 0, stream>>>(qkvb, logit_scale, rpbt, attn_b);
  // output projection with transposed (B,C,H,W) write
  gemm_mfma<128, 1><<<dim3(2048), dim3(256), 0, stream>>>(attn_b, proj_wb, proj_b, d_out,
                                                          (int)NPX, 256, 2);
}

// Round 11
// 609.773 us; speedup vs baseline: 1.0734x; 1.0424x over previous
//
#include <hip/hip_runtime.h>
#include <cstdio>
#include <cstddef>
#include <cstdint>

#define F_B 8
#define F_C 256
#define F_H 128
#define F_W 128
#define F_HW 16384

typedef __attribute__((ext_vector_type(8))) short short8;   // bf16x8 MFMA operand
typedef __attribute__((ext_vector_type(4))) short short4v;  // bf16x4
typedef __attribute__((ext_vector_type(4))) float float4v;  // MFMA accumulator

__device__ __forceinline__ unsigned short f2bf(float f) {
  union {
    float f;
    uint32_t u;
  } v;
  v.f = f;
  return (unsigned short)((v.u + 0x7fffu + ((v.u >> 16) & 1u)) >> 16);
}

__device__ __forceinline__ float bf2f(unsigned short u) {
  union {
    uint32_t u;
    float f;
  } v;
  v.u = ((uint32_t)u) << 16;
  return v.f;
}

__device__ __forceinline__ void async_copy16(const unsigned short* g, unsigned short* l) {
  __builtin_amdgcn_global_load_lds((const __attribute__((address_space(1))) void*)g,
                                   (__attribute__((address_space(3))) void*)l, 16, 0, 0);
}

// ---------------- aux: weight bf16 conversion + bias concat ----------------
__global__ void build_aux2(const float* __restrict__ Wq, const float* __restrict__ Wk,
                           const float* __restrict__ bq, const float* __restrict__ bk,
                           const float* __restrict__ q_bias, const float* __restrict__ v_bias,
                           const float* __restrict__ Wv, const float* __restrict__ qkv_w,
                           const float* __restrict__ proj_w, unsigned short* __restrict__ qk_wb,
                           float* __restrict__ qk_b, float* __restrict__ qkv_b,
                           unsigned short* __restrict__ Wvb, unsigned short* __restrict__ qkv_wb,
                           unsigned short* __restrict__ proj_wb) {
  int t = blockIdx.x * 256 + threadIdx.x;  // 768 blocks -> 196608 threads
  if (t < 8192) {
    qk_wb[t] = f2bf(Wq[t]);
    qk_wb[8192 + t] = f2bf(Wk[t]);
  }
  if (t < 65536) {
    Wvb[t] = f2bf(Wv[t]);
    proj_wb[t] = f2bf(proj_w[t]);
  }
  if (t < 196608) qkv_wb[t] = f2bf(qkv_w[t]);
  if (t < 32) {
    qk_b[t] = bq[t];
    qk_b[32 + t] = bk[t];
  }
  if (t < 256) {
    qkv_b[t] = q_bias[t];
    qkv_b[256 + t] = 0.0f;
    qkv_b[512 + t] = v_bias[t];
  }
}

// ---------------- CPB MLP table: tblS[225][8] = 16*sigmoid(mlp(coords)) -----
__device__ __forceinline__ float cpb_coord(int a) {
  float v = (float)(a - 7) * (8.0f / 7.0f);
  float lg = log2f(fabsf(v) + 1.0f) * (1.0f / 3.0f);  // /log2(8)
  return (v < 0.0f) ? -lg : lg;
}

__global__ void cpb_table(const float* __restrict__ w1, const float* __restrict__ b1,
                          const float* __restrict__ w2, float* __restrict__ tblS) {
  int e = blockIdx.x;  // 0..224
  int yi = e / 15, xi = e % 15;
  float ry = cpb_coord(yi), rx = cpb_coord(xi);
  __shared__ float hid[512];
  int t = threadIdx.x;  // 256
  for (int j = t; j < 512; j += 256) {
    float hv = w1[j * 2] * ry + w1[j * 2 + 1] * rx + b1[j];
    hid[j] = fmaxf(hv, 0.0f);
  }
  __syncthreads();
  if (t < 8) {
    float s = 0.0f;
    for (int j = 0; j < 512; j++) s += hid[j] * w2[t * 512 + j];
    tblS[e * 8 + t] = 16.0f / (1.0f + __expf(-s));
  }
}

// ---------------- rpbt[h][i][j] = tblS[e(i,j)*8+h]  (window-independent) ----
__global__ void build_rpbt(const float* __restrict__ tblS, float* __restrict__ rpbt) {
  int t = blockIdx.x * 256 + threadIdx.x;  // < 32768
  int h = t >> 12, i = (t >> 6) & 63, j = t & 63;
  int e = ((i >> 3) - (j >> 3) + 7) * 15 + ((i & 7) - (j & 7) + 7);
  rpbt[t] = tblS[e * 8 + h];
}

// ---------------- transpose (B,C,HW) -> (B,HW,C) bf16 ----------------
__global__ void transpose_bf(const float* __restrict__ in, unsigned short* __restrict__ outb) {
  __shared__ float tile[32][33];
  int b = blockIdx.z;
  int p0 = blockIdx.x * 32;
  int c0 = blockIdx.y * 32;
  const float* src = in + (size_t)b * F_C * F_HW;
  int tx = threadIdx.x, ty = threadIdx.y;  // 32 x 8
#pragma unroll
  for (int i = 0; i < 4; i++) {
    tile[ty + i * 8][tx] = src[(size_t)(c0 + ty + i * 8) * F_HW + p0 + tx];
  }
  __syncthreads();
#pragma unroll
  for (int i = 0; i < 4; i++) {
    size_t idx = (size_t)b * F_HW * F_C + (size_t)(p0 + ty + i * 8) * F_C + c0 + tx;
    outb[idx] = f2bf(tile[tx][ty + i * 8]);
  }
}

// ---------------- bf16 MFMA GEMM (round-8 form, 619us-verified) ----------
// 1-D grid with XCD-chunked swizzle; single-buffered LDS, 2 barriers/K-iter;
// swizzle f(r) = (r>>1)&3 both sides (conflict-free).
// OUT 0: fp32 row-major. OUT 1: fp32 out[((row>>14)*N+col)*16384+(row&16383)].
// OUT 2: bf16 row-major.
template <int BN, int OUT>
__global__ __launch_bounds__(256) void gemm_mfma(const unsigned short* __restrict__ A,
                                                 const unsigned short* __restrict__ Wt,
                                                 const float* __restrict__ bias, void* Cmat,
                                                 int M, int N, int gx) {
  constexpr int WN = BN / 2;
  constexpr int NREP = WN / 16;
  __shared__ __align__(16) unsigned short As[128 * 32];
  __shared__ __align__(16) unsigned short Bs[BN * 32];
  int nwg = gridDim.x;
  int id = blockIdx.x;
  int cpx = nwg >> 3;
  int swz = (id & 7) * cpx + (id >> 3);
  int by = swz / gx;
  int bx = swz - by * gx;
  int m0 = by * 128;
  int n0 = bx * BN;
  int t = threadIdx.x;
  int wid = t >> 6, lane = t & 63;
  int wr = wid >> 1, wc = wid & 1;

  float4v acc[4][NREP] = {};

  for (int k0 = 0; k0 < 256; k0 += 32) {
    __syncthreads();
#pragma unroll
    for (int j = 0; j < 2; j++) {
      int r = wid * 32 + j * 16 + (lane >> 2);
      int kg = (lane & 3) ^ ((r >> 1) & 3);  // inverse swizzle on global source
      const unsigned short* gp = A + (size_t)(m0 + r) * 256 + k0 + kg * 8;
      async_copy16(gp, As + (wid * 32 + j * 16) * 32);
    }
#pragma unroll
    for (int j = 0; j < BN / 64; j++) {
      int r = wid * (BN / 4) + j * 16 + (lane >> 2);
      int kg = (lane & 3) ^ ((r >> 1) & 3);
      const unsigned short* gp = Wt + (size_t)(n0 + r) * 256 + k0 + kg * 8;
      async_copy16(gp, Bs + (wid * (BN / 4) + j * 16) * 32);
    }
    __syncthreads();
    short8 af[4];
#pragma unroll
    for (int mi = 0; mi < 4; mi++) {
      int row = wr * 64 + mi * 16 + (lane & 15);
      int kg = (lane >> 4) ^ ((row >> 1) & 3);
      af[mi] = *(const short8*)(As + row * 32 + kg * 8);
    }
    short8 bfr[NREP];
#pragma unroll
    for (int ni = 0; ni < NREP; ni++) {
      int col = wc * WN + ni * 16 + (lane & 15);
      int kg = (lane >> 4) ^ ((col >> 1) & 3);
      bfr[ni] = *(const short8*)(Bs + col * 32 + kg * 8);
    }
#pragma unroll
    for (int mi = 0; mi < 4; mi++)
#pragma unroll
      for (int ni = 0; ni < NREP; ni++)
        acc[mi][ni] =
            __builtin_amdgcn_mfma_f32_16x16x32_bf16(af[mi], bfr[ni], acc[mi][ni], 0, 0, 0);
  }
#pragma unroll
  for (int ni = 0; ni < NREP; ni++) {
    int col = n0 + wc * WN + ni * 16 + (lane & 15);
    float bn = bias[col];
#pragma unroll
    for (int mi = 0; mi < 4; mi++) {
      int row0 = m0 + wr * 64 + mi * 16 + (lane >> 4) * 4;
#pragma unroll
      for (int r = 0; r < 4; r++) {
        float v = acc[mi][ni][r] + bn;
        int row = row0 + r;
        if (OUT == 0) {
          ((float*)Cmat)[(size_t)row * N + col] = v;
        } else if (OUT == 1) {
          int bb = row >> 14, p = row & 16383;
          ((float*)Cmat)[((size_t)bb * N + col) * F_HW + p] = v;
        } else {
          ((unsigned short*)Cmat)[(size_t)row * N + col] = f2bf(v);
        }
      }
    }
  }
}

// ---------------- criss-cross logits (bf16 exp output + partial row sum) ----
template <int MODE>
__global__ __launch_bounds__(256) void cc_logits(const float* __restrict__ qk,
                                                 unsigned short* __restrict__ e,
                                                 float* __restrict__ sums) {
  int x = blockIdx.x;
  int b = blockIdx.y;
  size_t base = (size_t)b * F_HW;
  __shared__ float kt[32][132];  // kt[c][g]
  int t = threadIdx.x;
  {
    int gk = t >> 1, c0 = (t & 1) * 16;
    size_t krow = (MODE == 0) ? ((size_t)gk * F_W + x) : ((size_t)x * F_W + gk);
    const float4* src = (const float4*)(qk + (base + krow) * 64 + 32 + c0);
#pragma unroll
    for (int q4 = 0; q4 < 4; q4++) {
      float4 v = src[q4];
      kt[c0 + q4 * 4 + 0][gk] = v.x;
      kt[c0 + q4 * 4 + 1][gk] = v.y;
      kt[c0 + q4 * 4 + 2][gk] = v.z;
      kt[c0 + q4 * 4 + 3][gk] = v.w;
    }
  }
  __syncthreads();
  int i = t >> 1, g0 = (t & 1) * 64;
  size_t qrow = (MODE == 0) ? ((size_t)i * F_W + x) : ((size_t)x * F_W + i);
  const float4* qp = (const float4*)(qk + (base + qrow) * 64);
  float qreg[32];
#pragma unroll
  for (int q4 = 0; q4 < 8; q4++) {
    float4 v = qp[q4];
    qreg[q4 * 4 + 0] = v.x;
    qreg[q4 * 4 + 1] = v.y;
    qreg[q4 * 4 + 2] = v.z;
    qreg[q4 * 4 + 3] = v.w;
  }
  float acc[64];
#pragma unroll
  for (int g = 0; g < 64; g++) acc[g] = 0.0f;
  for (int c = 0; c < 32; c++) {
    float qv = qreg[c];
#pragma unroll
    for (int g = 0; g < 64; g++) acc[g] += qv * kt[c][g0 + g];
  }
  if (MODE == 0) {
    int d = i - g0;
    if (d >= 0 && d < 64) acc[d] = -1e9f;  // diag mask -> exp = 0
  }
  unsigned short* ep = e + (base + qrow) * 256 + MODE * 128 + g0;
  float s = 0.0f;
#pragma unroll
  for (int g = 0; g < 64; g += 8) {
    short8 pk;
#pragma unroll
    for (int j = 0; j < 8; j++) {
      float ev = __expf(acc[g + j]);
      s += ev;
      pk[j] = (short)f2bf(ev);
    }
    *(short8*)(ep + g) = pk;
  }
  s += __shfl_xor(s, 1);  // pair (t, t^1) share the same row i
  if ((t & 1) == 0) sums[base + qrow] = s;
}

// ---------------- criss-cross PV, bf16 MFMA (round-8 form) ----------------
template <int MODE>
__global__ __launch_bounds__(256) void cc_pv_mfma(const unsigned short* __restrict__ eb,
                                                  const unsigned short* __restrict__ vtb,
                                                  const float* __restrict__ sumH,
                                                  const float* __restrict__ sumW,
                                                  const float* __restrict__ gamma,
                                                  const unsigned short* __restrict__ xb,
                                                  unsigned short* __restrict__ pob,
                                                  unsigned short* __restrict__ ccb) {
  int x = blockIdx.x, b = blockIdx.y;
  size_t base = (size_t)b * F_HW;
  __shared__ __align__(16) unsigned short As[128 * 128];  // [i][k], swizzled, 32 KB
  __shared__ __align__(16) unsigned short Vs[256 * 64];   // [c][k-chunk], swizzled, 32 KB
  int t = threadIdx.x;
  int wid = t >> 6, lane = t & 63;
  int wr = wid >> 1, wc = wid & 1;
  // ---- stage A = normalized e (bf16) ----
  {
    int i = t >> 1, half = t & 1;
    size_t pix = (MODE == 0) ? ((size_t)i * F_W + x) : ((size_t)x * F_W + i);
    float rv = 1.0f / (sumH[base + pix] + sumW[base + pix]);
    const unsigned short* ep = eb + (base + pix) * 256 + MODE * 128 + half * 64;
    int g = ((i >> 3) & 7) ^ (i & 7);
#pragma unroll
    for (int s = 0; s < 8; s++) {
      short8 vin = *(const short8*)(ep + s * 8);
      short8 vo;
#pragma unroll
      for (int j = 0; j < 8; j++) vo[j] = (short)f2bf(bf2f((unsigned short)vin[j]) * rv);
      int slot = (half * 8 + s) ^ g;  // g is 3-bit: half bit preserved
      *(short8*)(As + i * 128 + slot * 8) = vo;
    }
  }
  float4v acc[4][8] = {};
#pragma unroll
  for (int kc = 0; kc < 2; kc++) {
    __syncthreads();
    // ---- stage Vs[c][k] for k-chunk kc: in-register 8x8 transpose ----
    {
      int ko = t >> 5, cj = t & 31;
      short8 rowv[8];
#pragma unroll
      for (int r = 0; r < 8; r++) {
        int kk = kc * 64 + ko * 8 + r;
        size_t pixk = (MODE == 0) ? ((size_t)kk * F_W + x) : ((size_t)x * F_W + kk);
        rowv[r] = *(const short8*)(vtb + (base + pixk) * 256 + cj * 8);
      }
#pragma unroll
      for (int j = 0; j < 8; j++) {
        short8 col;
#pragma unroll
        for (int r = 0; r < 8; r++) col[r] = rowv[r][j];
        int c = cj * 8 + j;
        int slot = ko ^ ((c >> 3) & 7) ^ (c & 7);
        *(short8*)(Vs + c * 64 + slot * 8) = col;
      }
    }
    __syncthreads();
#pragma unroll
    for (int ksub = 0; ksub < 2; ksub++) {
      short8 af[4];
#pragma unroll
      for (int mi = 0; mi < 4; mi++) {
        int i = wr * 64 + mi * 16 + (lane & 15);
        int slot = (kc * 8 + ksub * 4 + (lane >> 4)) ^ ((i >> 3) & 7) ^ (i & 7);
        af[mi] = *(const short8*)(As + i * 128 + slot * 8);
      }
      short8 bfv[8];
#pragma unroll
      for (int ni = 0; ni < 8; ni++) {
        int c = wc * 128 + ni * 16 + (lane & 15);
        int slot = (ksub * 4 + (lane >> 4)) ^ ((c >> 3) & 7) ^ (c & 7);
        bfv[ni] = *(const short8*)(Vs + c * 64 + slot * 8);
      }
#pragma unroll
      for (int mi = 0; mi < 4; mi++)
#pragma unroll
        for (int ni = 0; ni < 8; ni++)
          acc[mi][ni] =
              __builtin_amdgcn_mfma_f32_16x16x32_bf16(af[mi], bfv[ni], acc[mi][ni], 0, 0, 0);
    }
  }
  // ---- epilogue ----
  float gm = gamma[0];
#pragma unroll
  for (int mi = 0; mi < 4; mi++) {
#pragma unroll
    for (int ni = 0; ni < 8; ni++) {
#pragma unroll
      for (int r = 0; r < 4; r++) {
        int i = wr * 64 + mi * 16 + (lane >> 4) * 4 + r;
        int c = wc * 128 + ni * 16 + (lane & 15);
        size_t pix = (MODE == 0) ? ((size_t)i * F_W + x) : ((size_t)x * F_W + i);
        size_t idx = (base + pix) * 256 + c;
        if (MODE == 0) {
          pob[idx] = f2bf(acc[mi][ni][r]);
        } else {
          float v = gm * (bf2f(pob[idx]) + acc[mi][ni][r]) + bf2f(xb[idx]);
          ccb[idx] = f2bf(v);
        }
      }
    }
  }
}

// ---------------- FUSED window qkv-GEMM + attention ----------------
// One block per window (64 pixels), 512 threads = 8 waves (wave = head).
// LDS 144 KB: As (window cc, 32K) | Bs dbuf (16K) | QKV bf16 (96K).
// Overlays after GEMM: Vt (8x4K) on As; Pl (8x8K) on QKV q+k sections.
// Math is bit-identical to the unfused gemm_mfma<128,2> + win_attn_mfma path.
__global__ __launch_bounds__(512, 2) void win_fused(
    const unsigned short* __restrict__ ccb, const unsigned short* __restrict__ qkv_wb,
    const float* __restrict__ qkv_b, const float* __restrict__ logit_scale,
    const float* __restrict__ rpbt, unsigned short* __restrict__ out) {
  __shared__ __align__(16) unsigned short As[64 * 256];       // 32 KB
  __shared__ __align__(16) unsigned short Bs[2][128 * 32];    // 16 KB
  __shared__ __align__(16) unsigned short QKV[3 * 64 * 256];  // 96 KB
  int tid = threadIdx.x;
  int wid = tid >> 6, lane = tid & 63;
  int il = lane & 15, kg = lane >> 4;
  int win = blockIdx.x;
  int b = win >> 8, wy = (win >> 4) & 15, wx = win & 15;
  size_t pbase = (size_t)b * F_HW + (size_t)(wy * 8) * F_W + wx * 8;

  // ---- stage As: window cc rows [n][c], swizzle slot = (c>>3) ^ (n&7) ----
#pragma unroll
  for (int i = 0; i < 4; i++) {
    int n = i * 16 + (tid >> 5);
    int slot = tid & 31;
    size_t srow = pbase + (size_t)(n >> 3) * F_W + (n & 7);
    async_copy16(ccb + srow * 256 + (size_t)(slot ^ (n & 7)) * 8, As + n * 256 + slot * 8);
  }

  // ---- GEMM: QKV[n][768] = cc @ Wqkv^T + bias; 6 chunks of 128 cols ----
  int rB = tid >> 2, ksB = tid & 3;
  int kgB = ksB ^ ((rB >> 1) & 3);
  for (int nc = 0; nc < 6; nc++) {
    int col0 = nc * 128;
    const unsigned short* wp = qkv_wb + (size_t)(col0 + rB) * 256 + kgB * 8;
    async_copy16(wp, Bs[0] + rB * 32 + ksB * 8);  // prologue k0=0
    __syncthreads();
    float4v acc[4] = {};
    int cur = 0;
    for (int k0 = 0; k0 < 256; k0 += 32) {
      if (k0 < 224) async_copy16(wp + k0 + 32, Bs[cur ^ 1] + rB * 32 + ksB * 8);
      int colW = wid * 16 + il;
      short8 bfr = *(const short8*)(Bs[cur] + colW * 32 + (kg ^ ((colW >> 1) & 3)) * 8);
#pragma unroll
      for (int mi = 0; mi < 4; mi++) {
        int row = mi * 16 + il;
        int slot = ((k0 >> 3) + kg) ^ (row & 7);
        short8 af = *(const short8*)(As + row * 256 + slot * 8);
        acc[mi] = __builtin_amdgcn_mfma_f32_16x16x32_bf16(af, bfr, acc[mi], 0, 0, 0);
      }
      __syncthreads();
      cur ^= 1;
    }
    // epilogue -> QKV LDS (bf16 + bias); C/D: col fixed, rows (kg*4 + r)
    int cg = col0 + wid * 16 + il;
    int sec = cg >> 8, cs = cg & 255;
    float bn = qkv_b[cg];
    unsigned short* qp = QKV + sec * 16384;
#pragma unroll
    for (int mi = 0; mi < 4; mi++) {
#pragma unroll
      for (int r = 0; r < 4; r++) {
        int n = mi * 16 + kg * 4 + r;
        qp[n * 256 + (((cs >> 3) ^ (n & 7)) * 8) + (cs & 7)] = f2bf(acc[mi][r] + bn);
      }
    }
  }
  __syncthreads();

  // ---- attention: wave = head hh = wid ----
  int hh = wid;
  unsigned short* Pl_w = QKV + wid * 4096;  // overlays q+k sections (dead after S)
  unsigned short* Vt_w = As + wid * 2048;   // overlays As (dead after GEMM)

  // load + cosine-normalize Q (B-frags) and K (A-frags) from LDS
  short8 qb[4], ka[4];
#pragma unroll
  for (int ni = 0; ni < 4; ni++) {
    int i = ni * 16 + il;
    int so = ((hh * 4 + kg) ^ (i & 7)) * 8;
    short8 qv = *(const short8*)(QKV + i * 256 + so);
    short8 kv = *(const short8*)(QKV + 16384 + i * 256 + so);
    float qss = 0.0f, kss = 0.0f;
#pragma unroll
    for (int j = 0; j < 8; j++) {
      float qf = bf2f((unsigned short)qv[j]);
      float kf = bf2f((unsigned short)kv[j]);
      qss += qf * qf;
      kss += kf * kf;
    }
    qss += __shfl_xor(qss, 16);
    qss += __shfl_xor(qss, 32);
    kss += __shfl_xor(kss, 16);
    kss += __shfl_xor(kss, 32);
    float qinv = 1.0f / fmaxf(sqrtf(qss), 1e-12f);
    float kinv = 1.0f / fmaxf(sqrtf(kss), 1e-12f);
#pragma unroll
    for (int j = 0; j < 8; j++) {
      qb[ni][j] = (short)f2bf(bf2f((unsigned short)qv[j]) * qinv);
      ka[ni][j] = (short)f2bf(bf2f((unsigned short)kv[j]) * kinv);
    }
  }

  // stage V^T[d][j] (lanes 0..31, in-register 8x8 transpose) from QKV v-sec
  if (lane < 32) {
    int jb = lane >> 2, db = lane & 3;
    short8 rows[8];
#pragma unroll
    for (int r = 0; r < 8; r++) {
      rows[r] = *(const short8*)(QKV + 32768 + (jb * 8 + r) * 256 + (((hh * 4 + db) ^ r) * 8));
    }
#pragma unroll
    for (int c = 0; c < 8; c++) {
      int d = db * 8 + c;
      short8 col;
#pragma unroll
      for (int r = 0; r < 8; r++) col[r] = rows[r][c];
      *(short8*)(Vt_w + d * 64 + ((jb ^ (d & 7)) * 8)) = col;
    }
  }

  // S^T = K @ Q^T
  float4v sacc[4][4] = {};
#pragma unroll
  for (int mj = 0; mj < 4; mj++)
#pragma unroll
    for (int ni = 0; ni < 4; ni++)
      sacc[mj][ni] =
          __builtin_amdgcn_mfma_f32_16x16x32_bf16(ka[mj], qb[ni], sacc[mj][ni], 0, 0, 0);

  float scale = __expf(fminf(logit_scale[hh], 4.605170185988091f));  // ln(100)
  __syncthreads();  // all waves done reading q,k before Pl overlay writes

  // softmax over j (per col i), write P[i][j] bf16 to Pl
#pragma unroll
  for (int ni = 0; ni < 4; ni++) {
    int i = ni * 16 + il;
    const float* rp = rpbt + ((size_t)hh * 64 + i) * 64;
    float sv[16];
    float mx = -1e30f;
#pragma unroll
    for (int mj = 0; mj < 4; mj++) {
      float4 rb = *(const float4*)(rp + mj * 16 + kg * 4);
      float rbs[4] = {rb.x, rb.y, rb.z, rb.w};
#pragma unroll
      for (int r = 0; r < 4; r++) {
        float v = sacc[mj][ni][r] * scale + rbs[r];
        sv[mj * 4 + r] = v;
        mx = fmaxf(mx, v);
      }
    }
    mx = fmaxf(mx, __shfl_xor(mx, 16));
    mx = fmaxf(mx, __shfl_xor(mx, 32));
    float sm = 0.0f;
#pragma unroll
    for (int u = 0; u < 16; u++) {
      sv[u] = __expf(sv[u] - mx);
      sm += sv[u];
    }
    sm += __shfl_xor(sm, 16);
    sm += __shfl_xor(sm, 32);
    float inv = 1.0f / sm;
#pragma unroll
    for (int mj = 0; mj < 4; mj++) {
      int j0 = mj * 16 + kg * 4;
      short4v pk;
#pragma unroll
      for (int r = 0; r < 4; r++) pk[r] = (short)f2bf(sv[mj * 4 + r] * inv);
      int byteoff = i * 128 + (((j0 >> 3) ^ (i & 7)) * 16) + (j0 & 7) * 2;
      *(short4v*)((char*)Pl_w + byteoff) = pk;
    }
  }
  __syncthreads();

  // O^T = V^T @ P^T
  float4v oacc[2][4] = {};
#pragma unroll
  for (int kc = 0; kc < 2; kc++) {
    short8 va[2];
#pragma unroll
    for (int md = 0; md < 2; md++) {
      int d = md * 16 + il;
      va[md] = *(const short8*)((char*)Vt_w + d * 128 + (((kc * 4 + kg) ^ (d & 7)) * 16));
    }
    short8 pb[4];
#pragma unroll
    for (int ni = 0; ni < 4; ni++) {
      int i = ni * 16 + il;
      pb[ni] = *(const short8*)((char*)Pl_w + i * 128 + (((kc * 4 + kg) ^ (i & 7)) * 16));
    }
#pragma unroll
    for (int md = 0; md < 2; md++)
#pragma unroll
      for (int ni = 0; ni < 4; ni++)
        oacc[md][ni] =
            __builtin_amdgcn_mfma_f32_16x16x32_bf16(va[md], pb[ni], oacc[md][ni], 0, 0, 0);
  }

  // write out: O^T col = i = lane&15, row d = md*16 + kg*4 + r
#pragma unroll
  for (int ni = 0; ni < 4; ni++) {
    int i = ni * 16 + il;
    size_t orow = (pbase + (size_t)(i >> 3) * F_W + (i & 7)) * 256 + hh * 32;
#pragma unroll
    for (int md = 0; md < 2; md++) {
      int d0 = md * 16 + kg * 4;
      short4v pk;
#pragma unroll
      for (int r = 0; r < 4; r++) pk[r] = (short)f2bf(oacc[md][ni][r]);
      *(short4v*)(out + orow + d0) = pk;
    }
  }
}

// ---------------- launch ----------------
extern "C" void kernel_launch(void* const* d_in, const int* in_sizes, int n_in,
                              void* d_out, int out_size, void* d_ws, size_t ws_size,
                              hipStream_t stream) {
  const float* x = (const float*)d_in[0];
  const float* y = (const float*)d_in[1];
  const float* Wq = (const float*)d_in[2];
  const float* bq = (const float*)d_in[3];
  const float* Wk = (const float*)d_in[4];
  const float* bk = (const float*)d_in[5];
  const float* Wv = (const float*)d_in[6];
  const float* bv = (const float*)d_in[7];
  const float* gamma = (const float*)d_in[8];
  const float* qkv_w = (const float*)d_in[9];
  const float* q_bias = (const float*)d_in[10];
  const float* v_bias = (const float*)d_in[11];
  const float* logit_scale = (const float*)d_in[12];
  const float* cpb_w1 = (const float*)d_in[13];
  const float* cpb_b1 = (const float*)d_in[14];
  const float* cpb_w2 = (const float*)d_in[15];
  const float* proj_w = (const float*)d_in[16];
  const float* proj_b = (const float*)d_in[17];

  float* ws = (float*)d_ws;
  const size_t NPX = (size_t)F_B * F_HW;  // 131072
  const size_t M1 = NPX * 256;            // 33.55M floats (bf16 plane = M1/2 floats)
  size_t f_xb = 0;                 // xb bf16
  size_t f_ytb = M1 / 2;           // ytb bf16; eb bf16 overlays after v-GEMM
  size_t f_vtb = M1;               // vtb bf16
  size_t f_pob = M1 + M1 / 2;      // pob bf16; attn_b bf16 overlays after pv
  size_t f_ccb = 2 * M1;           // ccb bf16
  size_t f_qkb = 2 * M1 + M1 / 2;  // qkb fp32 (NPX*64)
  size_t f_wts = f_qkb + NPX * 64;
  size_t o_qkwb = f_wts;              // 16384 ushort -> 8192 f
  size_t o_Wvb = o_qkwb + 8192;       // 65536 ushort -> 32768 f
  size_t o_qkvwb = o_Wvb + 32768;     // 196608 ushort -> 98304 f
  size_t o_projwb = o_qkvwb + 98304;  // 65536 ushort -> 32768 f
  size_t o_qkb2 = o_projwb + 32768;   // 64 f
  size_t o_qkvb2 = o_qkb2 + 64;       // 768 f
  size_t o_tbl = o_qkvb2 + 768;       // 1800 f
  size_t o_sumH = o_tbl + 1800;       // NPX f
  size_t o_sumW = o_sumH + NPX;       // NPX f
  size_t o_rpbt = o_sumW + NPX;       // 32768 f
  size_t need = (o_rpbt + 32768) * sizeof(float);
  if (ws_size < need) {
    fprintf(stderr, "kernel_launch: ws too small: %zu < %zu\n", ws_size, need);
    return;
  }
  unsigned short* xb = (unsigned short*)(ws + f_xb);
  unsigned short* ytb = (unsigned short*)(ws + f_ytb);
  unsigned short* eb = (unsigned short*)(ws + f_ytb);
  unsigned short* vtb = (unsigned short*)(ws + f_vtb);
  unsigned short* pob = (unsigned short*)(ws + f_pob);
  unsigned short* attn_b = (unsigned short*)(ws + f_pob);
  unsigned short* ccb = (unsigned short*)(ws + f_ccb);
  float* qkb = ws + f_qkb;
  unsigned short* qk_wb = (unsigned short*)(ws + o_qkwb);
  unsigned short* Wvb = (unsigned short*)(ws + o_Wvb);
  unsigned short* qkv_wb = (unsigned short*)(ws + o_qkvwb);
  unsigned short* proj_wb = (unsigned short*)(ws + o_projwb);
  float* qk_b = ws + o_qkb2;
  float* qkv_b = ws + o_qkvb2;
  float* tblS = ws + o_tbl;
  float* sumH = ws + o_sumH;
  float* sumW = ws + o_sumW;
  float* rpbt = ws + o_rpbt;

  build_aux2<<<dim3(768), dim3(256), 0, stream>>>(Wq, Wk, bq, bk, q_bias, v_bias, Wv, qkv_w,
                                                  proj_w, qk_wb, qk_b, qkv_b, Wvb, qkv_wb,
                                                  proj_wb);
  cpb_table<<<dim3(225), dim3(256), 0, stream>>>(cpb_w1, cpb_b1, cpb_w2, tblS);
  build_rpbt<<<dim3(128), dim3(256), 0, stream>>>(tblS, rpbt);
  // x^T -> xb bf16 ; y^T -> ytb bf16
  transpose_bf<<<dim3(512, 8, 8), dim3(32, 8), 0, stream>>>(x, xb);
  transpose_bf<<<dim3(512, 8, 8), dim3(32, 8), 0, stream>>>(y, ytb);
  // q|k projection: (BHW x 256) @ (64 x 256)^T -> fp32
  gemm_mfma<64, 0><<<dim3(1024), dim3(256), 0, stream>>>(xb, qk_wb, qk_b, qkb, (int)NPX, 64,
                                                         1);
  // v projection -> bf16 vtb
  gemm_mfma<128, 2><<<dim3(2048), dim3(256), 0, stream>>>(ytb, Wvb, bv, vtb, (int)NPX, 256, 2);
  // criss-cross attention (GEMM-structured, bf16 e, fused partial sums)
  cc_logits<0><<<dim3(128, 8), dim3(256), 0, stream>>>(qkb, eb, sumH);
  cc_logits<1><<<dim3(128, 8), dim3(256), 0, stream>>>(qkb, eb, sumW);
  cc_pv_mfma<0><<<dim3(128, 8), dim3(256), 0, stream>>>(eb, vtb, sumH, sumW, gamma, xb, pob,
                                                        ccb);
  cc_pv_mfma<1><<<dim3(128, 8), dim3(256), 0, stream>>>(eb, vtb, sumH, sumW, gamma, xb, pob,
                                                        ccb);
  // FUSED window qkv projection + window attention (no qkv materialization)
  win_fused<<<dim3(2048), dim3(512), 0, stream>>>(ccb, qkv_wb, qkv_b, logit_scale, rpbt,
                                                  attn_b);
  // output projection with transposed (B,C,H,W) write
  gemm_mfma<128, 1><<<dim3(2048), dim3(256), 0, stream>>>(attn_b, proj_wb, proj_b, d_out,
                                                          (int)NPX, 256, 2);
}

// Round 12
// 584.162 us; speedup vs baseline: 1.1204x; 1.0438x over previous
//
#include <hip/hip_runtime.h>
#include <cstdio>
#include <cstddef>
#include <cstdint>

#define F_B 8
#define F_C 256
#define F_H 128
#define F_W 128
#define F_HW 16384

typedef __attribute__((ext_vector_type(8))) short short8;   // bf16x8 MFMA operand
typedef __attribute__((ext_vector_type(4))) short short4v;  // bf16x4
typedef __attribute__((ext_vector_type(4))) float float4v;  // MFMA accumulator

__device__ __forceinline__ unsigned short f2bf(float f) {
  union {
    float f;
    uint32_t u;
  } v;
  v.f = f;
  return (unsigned short)((v.u + 0x7fffu + ((v.u >> 16) & 1u)) >> 16);
}

__device__ __forceinline__ float bf2f(unsigned short u) {
  union {
    uint32_t u;
    float f;
  } v;
  v.u = ((uint32_t)u) << 16;
  return v.f;
}

__device__ __forceinline__ void async_copy16(const unsigned short* g, unsigned short* l) {
  __builtin_amdgcn_global_load_lds((const __attribute__((address_space(1))) void*)g,
                                   (__attribute__((address_space(3))) void*)l, 16, 0, 0);
}

// ---------------- aux: weight bf16 conversion + bias concat ----------------
__global__ void build_aux2(const float* __restrict__ Wq, const float* __restrict__ Wk,
                           const float* __restrict__ bq, const float* __restrict__ bk,
                           const float* __restrict__ q_bias, const float* __restrict__ v_bias,
                           const float* __restrict__ Wv, const float* __restrict__ qkv_w,
                           const float* __restrict__ proj_w, unsigned short* __restrict__ qk_wb,
                           float* __restrict__ qk_b, float* __restrict__ qkv_b,
                           unsigned short* __restrict__ Wvb, unsigned short* __restrict__ qkv_wb,
                           unsigned short* __restrict__ proj_wb) {
  int t = blockIdx.x * 256 + threadIdx.x;  // 768 blocks -> 196608 threads
  if (t < 8192) {
    qk_wb[t] = f2bf(Wq[t]);
    qk_wb[8192 + t] = f2bf(Wk[t]);
  }
  if (t < 65536) {
    Wvb[t] = f2bf(Wv[t]);
    proj_wb[t] = f2bf(proj_w[t]);
  }
  if (t < 196608) qkv_wb[t] = f2bf(qkv_w[t]);
  if (t < 32) {
    qk_b[t] = bq[t];
    qk_b[32 + t] = bk[t];
  }
  if (t < 256) {
    qkv_b[t] = q_bias[t];
    qkv_b[256 + t] = 0.0f;
    qkv_b[512 + t] = v_bias[t];
  }
}

// ---------------- CPB MLP table: tblS[225][8] = 16*sigmoid(mlp(coords)) -----
__device__ __forceinline__ float cpb_coord(int a) {
  float v = (float)(a - 7) * (8.0f / 7.0f);
  float lg = log2f(fabsf(v) + 1.0f) * (1.0f / 3.0f);  // /log2(8)
  return (v < 0.0f) ? -lg : lg;
}

__global__ void cpb_table(const float* __restrict__ w1, const float* __restrict__ b1,
                          const float* __restrict__ w2, float* __restrict__ tblS) {
  int e = blockIdx.x;  // 0..224
  int yi = e / 15, xi = e % 15;
  float ry = cpb_coord(yi), rx = cpb_coord(xi);
  __shared__ float hid[512];
  int t = threadIdx.x;  // 256
  for (int j = t; j < 512; j += 256) {
    float hv = w1[j * 2] * ry + w1[j * 2 + 1] * rx + b1[j];
    hid[j] = fmaxf(hv, 0.0f);
  }
  __syncthreads();
  if (t < 8) {
    float s = 0.0f;
    for (int j = 0; j < 512; j++) s += hid[j] * w2[t * 512 + j];
    tblS[e * 8 + t] = 16.0f / (1.0f + __expf(-s));
  }
}

// ---------------- rpbt[h][i][j] = tblS[e(i,j)*8+h]  (window-independent) ----
__global__ void build_rpbt(const float* __restrict__ tblS, float* __restrict__ rpbt) {
  int t = blockIdx.x * 256 + threadIdx.x;  // < 32768
  int h = t >> 12, i = (t >> 6) & 63, j = t & 63;
  int e = ((i >> 3) - (j >> 3) + 7) * 15 + ((i & 7) - (j & 7) + 7);
  rpbt[t] = tblS[e * 8 + h];
}

// ---------------- transpose (B,C,HW) -> (B,HW,C) bf16 ----------------
__global__ void transpose_bf(const float* __restrict__ in, unsigned short* __restrict__ outb) {
  __shared__ float tile[32][33];
  int b = blockIdx.z;
  int p0 = blockIdx.x * 32;
  int c0 = blockIdx.y * 32;
  const float* src = in + (size_t)b * F_C * F_HW;
  int tx = threadIdx.x, ty = threadIdx.y;  // 32 x 8
#pragma unroll
  for (int i = 0; i < 4; i++) {
    tile[ty + i * 8][tx] = src[(size_t)(c0 + ty + i * 8) * F_HW + p0 + tx];
  }
  __syncthreads();
#pragma unroll
  for (int i = 0; i < 4; i++) {
    size_t idx = (size_t)b * F_HW * F_C + (size_t)(p0 + ty + i * 8) * F_C + c0 + tx;
    outb[idx] = f2bf(tile[tx][ty + i * 8]);
  }
}

// ---------------- bf16 MFMA GEMM (round-8 form, 619us-verified) ----------
template <int BN, int OUT>
__global__ __launch_bounds__(256) void gemm_mfma(const unsigned short* __restrict__ A,
                                                 const unsigned short* __restrict__ Wt,
                                                 const float* __restrict__ bias, void* Cmat,
                                                 int M, int N, int gx) {
  constexpr int WN = BN / 2;
  constexpr int NREP = WN / 16;
  __shared__ __align__(16) unsigned short As[128 * 32];
  __shared__ __align__(16) unsigned short Bs[BN * 32];
  int nwg = gridDim.x;
  int id = blockIdx.x;
  int cpx = nwg >> 3;
  int swz = (id & 7) * cpx + (id >> 3);
  int by = swz / gx;
  int bx = swz - by * gx;
  int m0 = by * 128;
  int n0 = bx * BN;
  int t = threadIdx.x;
  int wid = t >> 6, lane = t & 63;
  int wr = wid >> 1, wc = wid & 1;

  float4v acc[4][NREP] = {};

  for (int k0 = 0; k0 < 256; k0 += 32) {
    __syncthreads();
#pragma unroll
    for (int j = 0; j < 2; j++) {
      int r = wid * 32 + j * 16 + (lane >> 2);
      int kg = (lane & 3) ^ ((r >> 1) & 3);  // inverse swizzle on global source
      const unsigned short* gp = A + (size_t)(m0 + r) * 256 + k0 + kg * 8;
      async_copy16(gp, As + (wid * 32 + j * 16) * 32);
    }
#pragma unroll
    for (int j = 0; j < BN / 64; j++) {
      int r = wid * (BN / 4) + j * 16 + (lane >> 2);
      int kg = (lane & 3) ^ ((r >> 1) & 3);
      const unsigned short* gp = Wt + (size_t)(n0 + r) * 256 + k0 + kg * 8;
      async_copy16(gp, Bs + (wid * (BN / 4) + j * 16) * 32);
    }
    __syncthreads();
    short8 af[4];
#pragma unroll
    for (int mi = 0; mi < 4; mi++) {
      int row = wr * 64 + mi * 16 + (lane & 15);
      int kg = (lane >> 4) ^ ((row >> 1) & 3);
      af[mi] = *(const short8*)(As + row * 32 + kg * 8);
    }
    short8 bfr[NREP];
#pragma unroll
    for (int ni = 0; ni < NREP; ni++) {
      int col = wc * WN + ni * 16 + (lane & 15);
      int kg = (lane >> 4) ^ ((col >> 1) & 3);
      bfr[ni] = *(const short8*)(Bs + col * 32 + kg * 8);
    }
#pragma unroll
    for (int mi = 0; mi < 4; mi++)
#pragma unroll
      for (int ni = 0; ni < NREP; ni++)
        acc[mi][ni] =
            __builtin_amdgcn_mfma_f32_16x16x32_bf16(af[mi], bfr[ni], acc[mi][ni], 0, 0, 0);
  }
#pragma unroll
  for (int ni = 0; ni < NREP; ni++) {
    int col = n0 + wc * WN + ni * 16 + (lane & 15);
    float bn = bias[col];
#pragma unroll
    for (int mi = 0; mi < 4; mi++) {
      int row0 = m0 + wr * 64 + mi * 16 + (lane >> 4) * 4;
#pragma unroll
      for (int r = 0; r < 4; r++) {
        float v = acc[mi][ni][r] + bn;
        int row = row0 + r;
        if (OUT == 0) {
          ((float*)Cmat)[(size_t)row * N + col] = v;
        } else if (OUT == 1) {
          int bb = row >> 14, p = row & 16383;
          ((float*)Cmat)[((size_t)bb * N + col) * F_HW + p] = v;
        } else {
          ((unsigned short*)Cmat)[(size_t)row * N + col] = f2bf(v);
        }
      }
    }
  }
}

// ---------------- criss-cross logits (bf16 exp output + partial row sum) ----
template <int MODE>
__global__ __launch_bounds__(256) void cc_logits(const float* __restrict__ qk,
                                                 unsigned short* __restrict__ e,
                                                 float* __restrict__ sums) {
  int x = blockIdx.x;
  int b = blockIdx.y;
  size_t base = (size_t)b * F_HW;
  __shared__ float kt[32][132];  // kt[c][g]
  int t = threadIdx.x;
  {
    int gk = t >> 1, c0 = (t & 1) * 16;
    size_t krow = (MODE == 0) ? ((size_t)gk * F_W + x) : ((size_t)x * F_W + gk);
    const float4* src = (const float4*)(qk + (base + krow) * 64 + 32 + c0);
#pragma unroll
    for (int q4 = 0; q4 < 4; q4++) {
      float4 v = src[q4];
      kt[c0 + q4 * 4 + 0][gk] = v.x;
      kt[c0 + q4 * 4 + 1][gk] = v.y;
      kt[c0 + q4 * 4 + 2][gk] = v.z;
      kt[c0 + q4 * 4 + 3][gk] = v.w;
    }
  }
  __syncthreads();
  int i = t >> 1, g0 = (t & 1) * 64;
  size_t qrow = (MODE == 0) ? ((size_t)i * F_W + x) : ((size_t)x * F_W + i);
  const float4* qp = (const float4*)(qk + (base + qrow) * 64);
  float qreg[32];
#pragma unroll
  for (int q4 = 0; q4 < 8; q4++) {
    float4 v = qp[q4];
    qreg[q4 * 4 + 0] = v.x;
    qreg[q4 * 4 + 1] = v.y;
    qreg[q4 * 4 + 2] = v.z;
    qreg[q4 * 4 + 3] = v.w;
  }
  float acc[64];
#pragma unroll
  for (int g = 0; g < 64; g++) acc[g] = 0.0f;
  for (int c = 0; c < 32; c++) {
    float qv = qreg[c];
#pragma unroll
    for (int g = 0; g < 64; g++) acc[g] += qv * kt[c][g0 + g];
  }
  if (MODE == 0) {
    int d = i - g0;
    if (d >= 0 && d < 64) acc[d] = -1e9f;  // diag mask -> exp = 0
  }
  unsigned short* ep = e + (base + qrow) * 256 + MODE * 128 + g0;
  float s = 0.0f;
#pragma unroll
  for (int g = 0; g < 64; g += 8) {
    short8 pk;
#pragma unroll
    for (int j = 0; j < 8; j++) {
      float ev = __expf(acc[g + j]);
      s += ev;
      pk[j] = (short)f2bf(ev);
    }
    *(short8*)(ep + g) = pk;
  }
  s += __shfl_xor(s, 1);  // pair (t, t^1) share the same row i
  if ((t & 1) == 0) sums[base + qrow] = s;
}

// ---------------- criss-cross PV, bf16 MFMA (round-8 form) ----------------
template <int MODE>
__global__ __launch_bounds__(256) void cc_pv_mfma(const unsigned short* __restrict__ eb,
                                                  const unsigned short* __restrict__ vtb,
                                                  const float* __restrict__ sumH,
                                                  const float* __restrict__ sumW,
                                                  const float* __restrict__ gamma,
                                                  const unsigned short* __restrict__ xb,
                                                  unsigned short* __restrict__ pob,
                                                  unsigned short* __restrict__ ccb) {
  int x = blockIdx.x, b = blockIdx.y;
  size_t base = (size_t)b * F_HW;
  __shared__ __align__(16) unsigned short As[128 * 128];  // [i][k], swizzled, 32 KB
  __shared__ __align__(16) unsigned short Vs[256 * 64];   // [c][k-chunk], swizzled, 32 KB
  int t = threadIdx.x;
  int wid = t >> 6, lane = t & 63;
  int wr = wid >> 1, wc = wid & 1;
  // ---- stage A = normalized e (bf16) ----
  {
    int i = t >> 1, half = t & 1;
    size_t pix = (MODE == 0) ? ((size_t)i * F_W + x) : ((size_t)x * F_W + i);
    float rv = 1.0f / (sumH[base + pix] + sumW[base + pix]);
    const unsigned short* ep = eb + (base + pix) * 256 + MODE * 128 + half * 64;
    int g = ((i >> 3) & 7) ^ (i & 7);
#pragma unroll
    for (int s = 0; s < 8; s++) {
      short8 vin = *(const short8*)(ep + s * 8);
      short8 vo;
#pragma unroll
      for (int j = 0; j < 8; j++) vo[j] = (short)f2bf(bf2f((unsigned short)vin[j]) * rv);
      int slot = (half * 8 + s) ^ g;  // g is 3-bit: half bit preserved
      *(short8*)(As + i * 128 + slot * 8) = vo;
    }
  }
  float4v acc[4][8] = {};
#pragma unroll
  for (int kc = 0; kc < 2; kc++) {
    __syncthreads();
    // ---- stage Vs[c][k] for k-chunk kc: in-register 8x8 transpose ----
    {
      int ko = t >> 5, cj = t & 31;
      short8 rowv[8];
#pragma unroll
      for (int r = 0; r < 8; r++) {
        int kk = kc * 64 + ko * 8 + r;
        size_t pixk = (MODE == 0) ? ((size_t)kk * F_W + x) : ((size_t)x * F_W + kk);
        rowv[r] = *(const short8*)(vtb + (base + pixk) * 256 + cj * 8);
      }
#pragma unroll
      for (int j = 0; j < 8; j++) {
        short8 col;
#pragma unroll
        for (int r = 0; r < 8; r++) col[r] = rowv[r][j];
        int c = cj * 8 + j;
        int slot = ko ^ ((c >> 3) & 7) ^ (c & 7);
        *(short8*)(Vs + c * 64 + slot * 8) = col;
      }
    }
    __syncthreads();
#pragma unroll
    for (int ksub = 0; ksub < 2; ksub++) {
      short8 af[4];
#pragma unroll
      for (int mi = 0; mi < 4; mi++) {
        int i = wr * 64 + mi * 16 + (lane & 15);
        int slot = (kc * 8 + ksub * 4 + (lane >> 4)) ^ ((i >> 3) & 7) ^ (i & 7);
        af[mi] = *(const short8*)(As + i * 128 + slot * 8);
      }
      short8 bfv[8];
#pragma unroll
      for (int ni = 0; ni < 8; ni++) {
        int c = wc * 128 + ni * 16 + (lane & 15);
        int slot = (ksub * 4 + (lane >> 4)) ^ ((c >> 3) & 7) ^ (c & 7);
        bfv[ni] = *(const short8*)(Vs + c * 64 + slot * 8);
      }
#pragma unroll
      for (int mi = 0; mi < 4; mi++)
#pragma unroll
        for (int ni = 0; ni < 8; ni++)
          acc[mi][ni] =
              __builtin_amdgcn_mfma_f32_16x16x32_bf16(af[mi], bfv[ni], acc[mi][ni], 0, 0, 0);
    }
  }
  // ---- epilogue ----
  float gm = gamma[0];
#pragma unroll
  for (int mi = 0; mi < 4; mi++) {
#pragma unroll
    for (int ni = 0; ni < 8; ni++) {
#pragma unroll
      for (int r = 0; r < 4; r++) {
        int i = wr * 64 + mi * 16 + (lane >> 4) * 4 + r;
        int c = wc * 128 + ni * 16 + (lane & 15);
        size_t pix = (MODE == 0) ? ((size_t)i * F_W + x) : ((size_t)x * F_W + i);
        size_t idx = (base + pix) * 256 + c;
        if (MODE == 0) {
          pob[idx] = f2bf(acc[mi][ni][r]);
        } else {
          float v = gm * (bf2f(pob[idx]) + acc[mi][ni][r]) + bf2f(xb[idx]);
          ccb[idx] = f2bf(v);
        }
      }
    }
  }
}

// ---------------- FUSED window qkv-GEMM + attention (wave-autonomous) ------
// One block per window, 512 threads = 8 waves. LDS 144 KB:
//   As (window cc, 32K) | Bs per-wave dbuf (8 x 2 x 1K = 16K) | QKV bf16 (96K)
// GEMM: wave wid owns cols {nc*128 + wid*16 .. +16} -> Bs staging is
// WAVE-PRIVATE (one global_load_lds per k-step) -> ZERO barriers in the
// 6-chunk k-loop; waves drift and overlap each other's latency.
// Epilogue uses swapped mfma(bfr, af): pixel = lane&15, 4 consecutive weight
// cols = (lane>>4)*4+r  -> short4 LDS writes (4x fewer than scalar).
// Attention phase identical to round 11 (verified layouts).
__global__ __launch_bounds__(512, 2) void win_fused(
    const unsigned short* __restrict__ ccb, const unsigned short* __restrict__ qkv_wb,
    const float* __restrict__ qkv_b, const float* __restrict__ logit_scale,
    const float* __restrict__ rpbt, unsigned short* __restrict__ out) {
  __shared__ __align__(16) unsigned short As[64 * 256];       // 32 KB
  __shared__ __align__(16) unsigned short Bs[8][2][512];      // 16 KB per-wave dbuf
  __shared__ __align__(16) unsigned short QKV[3 * 64 * 256];  // 96 KB
  int tid = threadIdx.x;
  int wid = tid >> 6, lane = tid & 63;
  int il = lane & 15, kg = lane >> 4;
  int win = blockIdx.x;
  int b = win >> 8, wy = (win >> 4) & 15, wx = win & 15;
  size_t pbase = (size_t)b * F_HW + (size_t)(wy * 8) * F_W + wx * 8;

  // ---- stage As: window cc rows [n][c], swizzle slot = (c>>3) ^ (n&7) ----
#pragma unroll
  for (int i = 0; i < 4; i++) {
    int n = i * 16 + (tid >> 5);
    int slot = tid & 31;
    size_t srow = pbase + (size_t)(n >> 3) * F_W + (n & 7);
    async_copy16(ccb + srow * 256 + (size_t)(slot ^ (n & 7)) * 8, As + n * 256 + slot * 8);
  }
  __syncthreads();

  // ---- barrier-free per-wave GEMM over 6 chunks ----
  int r16 = lane >> 2, ks = lane & 3;
  int kgB = ks ^ ((r16 >> 1) & 3);  // inverse swizzle on global source
  unsigned short* Bw = &Bs[wid][0][0];
  for (int nc = 0; nc < 6; nc++) {
    int col0 = nc * 128;
    const unsigned short* wp = qkv_wb + (size_t)(col0 + wid * 16 + r16) * 256 + kgB * 8;
    async_copy16(wp, Bw + lane * 8);  // prologue: buf0, k0=0
    float4v acc[4] = {};
    int cur = 0;
    for (int k0 = 0; k0 < 256; k0 += 32) {
      short8 bfr = *(const short8*)(Bw + cur * 512 + il * 32 + (kg ^ ((il >> 1) & 3)) * 8);
      short8 af[4];
#pragma unroll
      for (int mi = 0; mi < 4; mi++) {
        int row = mi * 16 + il;
        int slot = ((k0 >> 3) + kg) ^ (row & 7);
        af[mi] = *(const short8*)(As + row * 256 + slot * 8);
      }
      if (k0 < 224) async_copy16(wp + k0 + 32, Bw + (cur ^ 1) * 512 + lane * 8);
      __builtin_amdgcn_s_setprio(1);
#pragma unroll
      for (int mi = 0; mi < 4; mi++)
        acc[mi] = __builtin_amdgcn_mfma_f32_16x16x32_bf16(bfr, af[mi], acc[mi], 0, 0, 0);
      __builtin_amdgcn_s_setprio(0);
      cur ^= 1;
    }
    // epilogue: pixel n = mi*16+il, cols cg..cg+3 -> one short4 LDS write
    int cg = col0 + wid * 16 + kg * 4;
    int sec = cg >> 8, cs = cg & 255;
    float4 bn4 = *(const float4*)(qkv_b + cg);
    float bns[4] = {bn4.x, bn4.y, bn4.z, bn4.w};
    unsigned short* qp = QKV + sec * 16384;
#pragma unroll
    for (int mi = 0; mi < 4; mi++) {
      int n = mi * 16 + il;
      short4v pk;
#pragma unroll
      for (int r = 0; r < 4; r++) pk[r] = (short)f2bf(acc[mi][r] + bns[r]);
      *(short4v*)(qp + n * 256 + (((cs >> 3) ^ (n & 7)) * 8) + (cs & 7)) = pk;
    }
  }
  __syncthreads();

  // ---- attention: wave = head hh = wid ----
  int hh = wid;
  unsigned short* Pl_w = QKV + wid * 4096;  // overlays q+k sections (dead after S)
  unsigned short* Vt_w = As + wid * 2048;   // overlays As (dead after GEMM)

  // load + cosine-normalize Q (B-frags) and K (A-frags) from LDS
  short8 qb[4], ka[4];
#pragma unroll
  for (int ni = 0; ni < 4; ni++) {
    int i = ni * 16 + il;
    int so = ((hh * 4 + kg) ^ (i & 7)) * 8;
    short8 qv = *(const short8*)(QKV + i * 256 + so);
    short8 kv = *(const short8*)(QKV + 16384 + i * 256 + so);
    float qss = 0.0f, kss = 0.0f;
#pragma unroll
    for (int j = 0; j < 8; j++) {
      float qf = bf2f((unsigned short)qv[j]);
      float kf = bf2f((unsigned short)kv[j]);
      qss += qf * qf;
      kss += kf * kf;
    }
    qss += __shfl_xor(qss, 16);
    qss += __shfl_xor(qss, 32);
    kss += __shfl_xor(kss, 16);
    kss += __shfl_xor(kss, 32);
    float qinv = 1.0f / fmaxf(sqrtf(qss), 1e-12f);
    float kinv = 1.0f / fmaxf(sqrtf(kss), 1e-12f);
#pragma unroll
    for (int j = 0; j < 8; j++) {
      qb[ni][j] = (short)f2bf(bf2f((unsigned short)qv[j]) * qinv);
      ka[ni][j] = (short)f2bf(bf2f((unsigned short)kv[j]) * kinv);
    }
  }

  // stage V^T[d][j] (lanes 0..31, in-register 8x8 transpose) from QKV v-sec
  if (lane < 32) {
    int jb = lane >> 2, db = lane & 3;
    short8 rows[8];
#pragma unroll
    for (int r = 0; r < 8; r++) {
      rows[r] = *(const short8*)(QKV + 32768 + (jb * 8 + r) * 256 + (((hh * 4 + db) ^ r) * 8));
    }
#pragma unroll
    for (int c = 0; c < 8; c++) {
      int d = db * 8 + c;
      short8 col;
#pragma unroll
      for (int r = 0; r < 8; r++) col[r] = rows[r][c];
      *(short8*)(Vt_w + d * 64 + ((jb ^ (d & 7)) * 8)) = col;
    }
  }

  // S^T = K @ Q^T
  float4v sacc[4][4] = {};
#pragma unroll
  for (int mj = 0; mj < 4; mj++)
#pragma unroll
    for (int ni = 0; ni < 4; ni++)
      sacc[mj][ni] =
          __builtin_amdgcn_mfma_f32_16x16x32_bf16(ka[mj], qb[ni], sacc[mj][ni], 0, 0, 0);

  float scale = __expf(fminf(logit_scale[hh], 4.605170185988091f));  // ln(100)
  __syncthreads();  // all waves done reading q,k before Pl overlay writes

  // softmax over j (per col i), write P[i][j] bf16 to Pl
#pragma unroll
  for (int ni = 0; ni < 4; ni++) {
    int i = ni * 16 + il;
    const float* rp = rpbt + ((size_t)hh * 64 + i) * 64;
    float sv[16];
    float mx = -1e30f;
#pragma unroll
    for (int mj = 0; mj < 4; mj++) {
      float4 rb = *(const float4*)(rp + mj * 16 + kg * 4);
      float rbs[4] = {rb.x, rb.y, rb.z, rb.w};
#pragma unroll
      for (int r = 0; r < 4; r++) {
        float v = sacc[mj][ni][r] * scale + rbs[r];
        sv[mj * 4 + r] = v;
        mx = fmaxf(mx, v);
      }
    }
    mx = fmaxf(mx, __shfl_xor(mx, 16));
    mx = fmaxf(mx, __shfl_xor(mx, 32));
    float sm = 0.0f;
#pragma unroll
    for (int u = 0; u < 16; u++) {
      sv[u] = __expf(sv[u] - mx);
      sm += sv[u];
    }
    sm += __shfl_xor(sm, 16);
    sm += __shfl_xor(sm, 32);
    float inv = 1.0f / sm;
#pragma unroll
    for (int mj = 0; mj < 4; mj++) {
      int j0 = mj * 16 + kg * 4;
      short4v pk;
#pragma unroll
      for (int r = 0; r < 4; r++) pk[r] = (short)f2bf(sv[mj * 4 + r] * inv);
      int byteoff = i * 128 + (((j0 >> 3) ^ (i & 7)) * 16) + (j0 & 7) * 2;
      *(short4v*)((char*)Pl_w + byteoff) = pk;
    }
  }
  __syncthreads();

  // O^T = V^T @ P^T
  float4v oacc[2][4] = {};
#pragma unroll
  for (int kc = 0; kc < 2; kc++) {
    short8 va[2];
#pragma unroll
    for (int md = 0; md < 2; md++) {
      int d = md * 16 + il;
      va[md] = *(const short8*)((char*)Vt_w + d * 128 + (((kc * 4 + kg) ^ (d & 7)) * 16));
    }
    short8 pb[4];
#pragma unroll
    for (int ni = 0; ni < 4; ni++) {
      int i = ni * 16 + il;
      pb[ni] = *(const short8*)((char*)Pl_w + i * 128 + (((kc * 4 + kg) ^ (i & 7)) * 16));
    }
#pragma unroll
    for (int md = 0; md < 2; md++)
#pragma unroll
      for (int ni = 0; ni < 4; ni++)
        oacc[md][ni] =
            __builtin_amdgcn_mfma_f32_16x16x32_bf16(va[md], pb[ni], oacc[md][ni], 0, 0, 0);
  }

  // write out: O^T col = i = lane&15, row d = md*16 + kg*4 + r
#pragma unroll
  for (int ni = 0; ni < 4; ni++) {
    int i = ni * 16 + il;
    size_t orow = (pbase + (size_t)(i >> 3) * F_W + (i & 7)) * 256 + hh * 32;
#pragma unroll
    for (int md = 0; md < 2; md++) {
      int d0 = md * 16 + kg * 4;
      short4v pk;
#pragma unroll
      for (int r = 0; r < 4; r++) pk[r] = (short)f2bf(oacc[md][ni][r]);
      *(short4v*)(out + orow + d0) = pk;
    }
  }
}

// ---------------- launch ----------------
extern "C" void kernel_launch(void* const* d_in, const int* in_sizes, int n_in,
                              void* d_out, int out_size, void* d_ws, size_t ws_size,
                              hipStream_t stream) {
  const float* x = (const float*)d_in[0];
  const float* y = (const float*)d_in[1];
  const float* Wq = (const float*)d_in[2];
  const float* bq = (const float*)d_in[3];
  const float* Wk = (const float*)d_in[4];
  const float* bk = (const float*)d_in[5];
  const float* Wv = (const float*)d_in[6];
  const float* bv = (const float*)d_in[7];
  const float* gamma = (const float*)d_in[8];
  const float* qkv_w = (const float*)d_in[9];
  const float* q_bias = (const float*)d_in[10];
  const float* v_bias = (const float*)d_in[11];
  const float* logit_scale = (const float*)d_in[12];
  const float* cpb_w1 = (const float*)d_in[13];
  const float* cpb_b1 = (const float*)d_in[14];
  const float* cpb_w2 = (const float*)d_in[15];
  const float* proj_w = (const float*)d_in[16];
  const float* proj_b = (const float*)d_in[17];

  float* ws = (float*)d_ws;
  const size_t NPX = (size_t)F_B * F_HW;  // 131072
  const size_t M1 = NPX * 256;            // 33.55M floats (bf16 plane = M1/2 floats)
  size_t f_xb = 0;                 // xb bf16
  size_t f_ytb = M1 / 2;           // ytb bf16; eb bf16 overlays after v-GEMM
  size_t f_vtb = M1;               // vtb bf16
  size_t f_pob = M1 + M1 / 2;      // pob bf16; attn_b bf16 overlays after pv
  size_t f_ccb = 2 * M1;           // ccb bf16
  size_t f_qkb = 2 * M1 + M1 / 2;  // qkb fp32 (NPX*64)
  size_t f_wts = f_qkb + NPX * 64;
  size_t o_qkwb = f_wts;              // 16384 ushort -> 8192 f
  size_t o_Wvb = o_qkwb + 8192;       // 65536 ushort -> 32768 f
  size_t o_qkvwb = o_Wvb + 32768;     // 196608 ushort -> 98304 f
  size_t o_projwb = o_qkvwb + 98304;  // 65536 ushort -> 32768 f
  size_t o_qkb2 = o_projwb + 32768;   // 64 f
  size_t o_qkvb2 = o_qkb2 + 64;       // 768 f
  size_t o_tbl = o_qkvb2 + 768;       // 1800 f
  size_t o_sumH = o_tbl + 1800;       // NPX f
  size_t o_sumW = o_sumH + NPX;       // NPX f
  size_t o_rpbt = o_sumW + NPX;       // 32768 f
  size_t need = (o_rpbt + 32768) * sizeof(float);
  if (ws_size < need) {
    fprintf(stderr, "kernel_launch: ws too small: %zu < %zu\n", ws_size, need);
    return;
  }
  unsigned short* xb = (unsigned short*)(ws + f_xb);
  unsigned short* ytb = (unsigned short*)(ws + f_ytb);
  unsigned short* eb = (unsigned short*)(ws + f_ytb);
  unsigned short* vtb = (unsigned short*)(ws + f_vtb);
  unsigned short* pob = (unsigned short*)(ws + f_pob);
  unsigned short* attn_b = (unsigned short*)(ws + f_pob);
  unsigned short* ccb = (unsigned short*)(ws + f_ccb);
  float* qkb = ws + f_qkb;
  unsigned short* qk_wb = (unsigned short*)(ws + o_qkwb);
  unsigned short* Wvb = (unsigned short*)(ws + o_Wvb);
  unsigned short* qkv_wb = (unsigned short*)(ws + o_qkvwb);
  unsigned short* proj_wb = (unsigned short*)(ws + o_projwb);
  float* qk_b = ws + o_qkb2;
  float* qkv_b = ws + o_qkvb2;
  float* tblS = ws + o_tbl;
  float* sumH = ws + o_sumH;
  float* sumW = ws + o_sumW;
  float* rpbt = ws + o_rpbt;

  build_aux2<<<dim3(768), dim3(256), 0, stream>>>(Wq, Wk, bq, bk, q_bias, v_bias, Wv, qkv_w,
                                                  proj_w, qk_wb, qk_b, qkv_b, Wvb, qkv_wb,
                                                  proj_wb);
  cpb_table<<<dim3(225), dim3(256), 0, stream>>>(cpb_w1, cpb_b1, cpb_w2, tblS);
  build_rpbt<<<dim3(128), dim3(256), 0, stream>>>(tblS, rpbt);
  // x^T -> xb bf16 ; y^T -> ytb bf16
  transpose_bf<<<dim3(512, 8, 8), dim3(32, 8), 0, stream>>>(x, xb);
  transpose_bf<<<dim3(512, 8, 8), dim3(32, 8), 0, stream>>>(y, ytb);
  // q|k projection: (BHW x 256) @ (64 x 256)^T -> fp32
  gemm_mfma<64, 0><<<dim3(1024), dim3(256), 0, stream>>>(xb, qk_wb, qk_b, qkb, (int)NPX, 64,
                                                         1);
  // v projection -> bf16 vtb
  gemm_mfma<128, 2><<<dim3(2048), dim3(256), 0, stream>>>(ytb, Wvb, bv, vtb, (int)NPX, 256, 2);
  // criss-cross attention (GEMM-structured, bf16 e, fused partial sums)
  cc_logits<0><<<dim3(128, 8), dim3(256), 0, stream>>>(qkb, eb, sumH);
  cc_logits<1><<<dim3(128, 8), dim3(256), 0, stream>>>(qkb, eb, sumW);
  cc_pv_mfma<0><<<dim3(128, 8), dim3(256), 0, stream>>>(eb, vtb, sumH, sumW, gamma, xb, pob,
                                                        ccb);
  cc_pv_mfma<1><<<dim3(128, 8), dim3(256), 0, stream>>>(eb, vtb, sumH, sumW, gamma, xb, pob,
                                                        ccb);
  // FUSED window qkv projection + window attention (wave-autonomous GEMM)
  win_fused<<<dim3(2048), dim3(512), 0, stream>>>(ccb, qkv_wb, qkv_b, logit_scale, rpbt,
                                                  attn_b);
  // output projection with transposed (B,C,H,W) write
  gemm_mfma<128, 1><<<dim3(2048), dim3(256), 0, stream>>>(attn_b, proj_wb, proj_b, d_out,
                                                          (int)NPX, 256, 2);
}

// Round 13
// 563.573 us; speedup vs baseline: 1.1614x; 1.0365x over previous
//
#include <hip/hip_runtime.h>
#include <cstdio>
#include <cstddef>
#include <cstdint>

#define F_B 8
#define F_C 256
#define F_H 128
#define F_W 128
#define F_HW 16384

typedef __attribute__((ext_vector_type(8))) short short8;   // bf16x8 MFMA operand
typedef __attribute__((ext_vector_type(4))) short short4v;  // bf16x4
typedef __attribute__((ext_vector_type(4))) float float4v;  // MFMA accumulator

__device__ __forceinline__ unsigned short f2bf(float f) {
  union {
    float f;
    uint32_t u;
  } v;
  v.f = f;
  return (unsigned short)((v.u + 0x7fffu + ((v.u >> 16) & 1u)) >> 16);
}

__device__ __forceinline__ float bf2f(unsigned short u) {
  union {
    uint32_t u;
    float f;
  } v;
  v.u = ((uint32_t)u) << 16;
  return v.f;
}

__device__ __forceinline__ void async_copy16(const unsigned short* g, unsigned short* l) {
  __builtin_amdgcn_global_load_lds((const __attribute__((address_space(1))) void*)g,
                                   (__attribute__((address_space(3))) void*)l, 16, 0, 0);
}

// ---------------- aux: weight bf16 conversion + bias concat ----------------
__global__ void build_aux2(const float* __restrict__ Wq, const float* __restrict__ Wk,
                           const float* __restrict__ bq, const float* __restrict__ bk,
                           const float* __restrict__ q_bias, const float* __restrict__ v_bias,
                           const float* __restrict__ Wv, const float* __restrict__ qkv_w,
                           const float* __restrict__ proj_w, unsigned short* __restrict__ qk_wb,
                           float* __restrict__ qk_b, float* __restrict__ qkv_b,
                           unsigned short* __restrict__ Wvb, unsigned short* __restrict__ qkv_wb,
                           unsigned short* __restrict__ proj_wb) {
  int t = blockIdx.x * 256 + threadIdx.x;  // 768 blocks -> 196608 threads
  if (t < 8192) {
    qk_wb[t] = f2bf(Wq[t]);
    qk_wb[8192 + t] = f2bf(Wk[t]);
  }
  if (t < 65536) {
    Wvb[t] = f2bf(Wv[t]);
    proj_wb[t] = f2bf(proj_w[t]);
  }
  if (t < 196608) qkv_wb[t] = f2bf(qkv_w[t]);
  if (t < 32) {
    qk_b[t] = bq[t];
    qk_b[32 + t] = bk[t];
  }
  if (t < 256) {
    qkv_b[t] = q_bias[t];
    qkv_b[256 + t] = 0.0f;
    qkv_b[512 + t] = v_bias[t];
  }
}

// ---------------- CPB MLP table: tblS[225][8] = 16*sigmoid(mlp(coords)) -----
__device__ __forceinline__ float cpb_coord(int a) {
  float v = (float)(a - 7) * (8.0f / 7.0f);
  float lg = log2f(fabsf(v) + 1.0f) * (1.0f / 3.0f);  // /log2(8)
  return (v < 0.0f) ? -lg : lg;
}

__global__ void cpb_table(const float* __restrict__ w1, const float* __restrict__ b1,
                          const float* __restrict__ w2, float* __restrict__ tblS) {
  int e = blockIdx.x;  // 0..224
  int yi = e / 15, xi = e % 15;
  float ry = cpb_coord(yi), rx = cpb_coord(xi);
  __shared__ float hid[512];
  int t = threadIdx.x;  // 256
  for (int j = t; j < 512; j += 256) {
    float hv = w1[j * 2] * ry + w1[j * 2 + 1] * rx + b1[j];
    hid[j] = fmaxf(hv, 0.0f);
  }
  __syncthreads();
  if (t < 8) {
    float s = 0.0f;
    for (int j = 0; j < 512; j++) s += hid[j] * w2[t * 512 + j];
    tblS[e * 8 + t] = 16.0f / (1.0f + __expf(-s));
  }
}

// ---------------- rpbt[h][i][j] = tblS[e(i,j)*8+h]  (window-independent) ----
__global__ void build_rpbt(const float* __restrict__ tblS, float* __restrict__ rpbt) {
  int t = blockIdx.x * 256 + threadIdx.x;  // < 32768
  int h = t >> 12, i = (t >> 6) & 63, j = t & 63;
  int e = ((i >> 3) - (j >> 3) + 7) * 15 + ((i & 7) - (j & 7) + 7);
  rpbt[t] = tblS[e * 8 + h];
}

// ---------------- transpose (B,C,HW) -> (B,HW,C) bf16 ----------------
__global__ void transpose_bf(const float* __restrict__ in, unsigned short* __restrict__ outb) {
  __shared__ float tile[32][33];
  int b = blockIdx.z;
  int p0 = blockIdx.x * 32;
  int c0 = blockIdx.y * 32;
  const float* src = in + (size_t)b * F_C * F_HW;
  int tx = threadIdx.x, ty = threadIdx.y;  // 32 x 8
#pragma unroll
  for (int i = 0; i < 4; i++) {
    tile[ty + i * 8][tx] = src[(size_t)(c0 + ty + i * 8) * F_HW + p0 + tx];
  }
  __syncthreads();
#pragma unroll
  for (int i = 0; i < 4; i++) {
    size_t idx = (size_t)b * F_HW * F_C + (size_t)(p0 + ty + i * 8) * F_C + c0 + tx;
    outb[idx] = f2bf(tile[tx][ty + i * 8]);
  }
}

// ---------------- bf16 MFMA GEMM (round-8 form, 619us-verified) ----------
template <int BN, int OUT>
__global__ __launch_bounds__(256) void gemm_mfma(const unsigned short* __restrict__ A,
                                                 const unsigned short* __restrict__ Wt,
                                                 const float* __restrict__ bias, void* Cmat,
                                                 int M, int N, int gx) {
  constexpr int WN = BN / 2;
  constexpr int NREP = WN / 16;
  __shared__ __align__(16) unsigned short As[128 * 32];
  __shared__ __align__(16) unsigned short Bs[BN * 32];
  int nwg = gridDim.x;
  int id = blockIdx.x;
  int cpx = nwg >> 3;
  int swz = (id & 7) * cpx + (id >> 3);
  int by = swz / gx;
  int bx = swz - by * gx;
  int m0 = by * 128;
  int n0 = bx * BN;
  int t = threadIdx.x;
  int wid = t >> 6, lane = t & 63;
  int wr = wid >> 1, wc = wid & 1;

  float4v acc[4][NREP] = {};

  for (int k0 = 0; k0 < 256; k0 += 32) {
    __syncthreads();
#pragma unroll
    for (int j = 0; j < 2; j++) {
      int r = wid * 32 + j * 16 + (lane >> 2);
      int kg = (lane & 3) ^ ((r >> 1) & 3);  // inverse swizzle on global source
      const unsigned short* gp = A + (size_t)(m0 + r) * 256 + k0 + kg * 8;
      async_copy16(gp, As + (wid * 32 + j * 16) * 32);
    }
#pragma unroll
    for (int j = 0; j < BN / 64; j++) {
      int r = wid * (BN / 4) + j * 16 + (lane >> 2);
      int kg = (lane & 3) ^ ((r >> 1) & 3);
      const unsigned short* gp = Wt + (size_t)(n0 + r) * 256 + k0 + kg * 8;
      async_copy16(gp, Bs + (wid * (BN / 4) + j * 16) * 32);
    }
    __syncthreads();
    short8 af[4];
#pragma unroll
    for (int mi = 0; mi < 4; mi++) {
      int row = wr * 64 + mi * 16 + (lane & 15);
      int kg = (lane >> 4) ^ ((row >> 1) & 3);
      af[mi] = *(const short8*)(As + row * 32 + kg * 8);
    }
    short8 bfr[NREP];
#pragma unroll
    for (int ni = 0; ni < NREP; ni++) {
      int col = wc * WN + ni * 16 + (lane & 15);
      int kg = (lane >> 4) ^ ((col >> 1) & 3);
      bfr[ni] = *(const short8*)(Bs + col * 32 + kg * 8);
    }
#pragma unroll
    for (int mi = 0; mi < 4; mi++)
#pragma unroll
      for (int ni = 0; ni < NREP; ni++)
        acc[mi][ni] =
            __builtin_amdgcn_mfma_f32_16x16x32_bf16(af[mi], bfr[ni], acc[mi][ni], 0, 0, 0);
  }
#pragma unroll
  for (int ni = 0; ni < NREP; ni++) {
    int col = n0 + wc * WN + ni * 16 + (lane & 15);
    float bn = bias[col];
#pragma unroll
    for (int mi = 0; mi < 4; mi++) {
      int row0 = m0 + wr * 64 + mi * 16 + (lane >> 4) * 4;
#pragma unroll
      for (int r = 0; r < 4; r++) {
        float v = acc[mi][ni][r] + bn;
        int row = row0 + r;
        if (OUT == 0) {
          ((float*)Cmat)[(size_t)row * N + col] = v;
        } else if (OUT == 1) {
          int bb = row >> 14, p = row & 16383;
          ((float*)Cmat)[((size_t)bb * N + col) * F_HW + p] = v;
        } else {
          ((unsigned short*)Cmat)[(size_t)row * N + col] = f2bf(v);
        }
      }
    }
  }
}

// ---------------- criss-cross logits (bf16 exp output + partial row sum) ----
template <int MODE>
__global__ __launch_bounds__(256) void cc_logits(const float* __restrict__ qk,
                                                 unsigned short* __restrict__ e,
                                                 float* __restrict__ sums) {
  int x = blockIdx.x;
  int b = blockIdx.y;
  size_t base = (size_t)b * F_HW;
  __shared__ float kt[32][132];  // kt[c][g]
  int t = threadIdx.x;
  {
    int gk = t >> 1, c0 = (t & 1) * 16;
    size_t krow = (MODE == 0) ? ((size_t)gk * F_W + x) : ((size_t)x * F_W + gk);
    const float4* src = (const float4*)(qk + (base + krow) * 64 + 32 + c0);
#pragma unroll
    for (int q4 = 0; q4 < 4; q4++) {
      float4 v = src[q4];
      kt[c0 + q4 * 4 + 0][gk] = v.x;
      kt[c0 + q4 * 4 + 1][gk] = v.y;
      kt[c0 + q4 * 4 + 2][gk] = v.z;
      kt[c0 + q4 * 4 + 3][gk] = v.w;
    }
  }
  __syncthreads();
  int i = t >> 1, g0 = (t & 1) * 64;
  size_t qrow = (MODE == 0) ? ((size_t)i * F_W + x) : ((size_t)x * F_W + i);
  const float4* qp = (const float4*)(qk + (base + qrow) * 64);
  float qreg[32];
#pragma unroll
  for (int q4 = 0; q4 < 8; q4++) {
    float4 v = qp[q4];
    qreg[q4 * 4 + 0] = v.x;
    qreg[q4 * 4 + 1] = v.y;
    qreg[q4 * 4 + 2] = v.z;
    qreg[q4 * 4 + 3] = v.w;
  }
  float acc[64];
#pragma unroll
  for (int g = 0; g < 64; g++) acc[g] = 0.0f;
  for (int c = 0; c < 32; c++) {
    float qv = qreg[c];
#pragma unroll
    for (int g = 0; g < 64; g++) acc[g] += qv * kt[c][g0 + g];
  }
  if (MODE == 0) {
    int d = i - g0;
    if (d >= 0 && d < 64) acc[d] = -1e9f;  // diag mask -> exp = 0
  }
  unsigned short* ep = e + (base + qrow) * 256 + MODE * 128 + g0;
  float s = 0.0f;
#pragma unroll
  for (int g = 0; g < 64; g += 8) {
    short8 pk;
#pragma unroll
    for (int j = 0; j < 8; j++) {
      float ev = __expf(acc[g + j]);
      s += ev;
      pk[j] = (short)f2bf(ev);
    }
    *(short8*)(ep + g) = pk;
  }
  s += __shfl_xor(s, 1);  // pair (t, t^1) share the same row i
  if ((t & 1) == 0) sums[base + qrow] = s;
}

// ---------------- criss-cross PV, bf16 MFMA (round-8 form) ----------------
template <int MODE>
__global__ __launch_bounds__(256) void cc_pv_mfma(const unsigned short* __restrict__ eb,
                                                  const unsigned short* __restrict__ vtb,
                                                  const float* __restrict__ sumH,
                                                  const float* __restrict__ sumW,
                                                  const float* __restrict__ gamma,
                                                  const unsigned short* __restrict__ xb,
                                                  unsigned short* __restrict__ pob,
                                                  unsigned short* __restrict__ ccb) {
  int x = blockIdx.x, b = blockIdx.y;
  size_t base = (size_t)b * F_HW;
  __shared__ __align__(16) unsigned short As[128 * 128];  // [i][k], swizzled, 32 KB
  __shared__ __align__(16) unsigned short Vs[256 * 64];   // [c][k-chunk], swizzled, 32 KB
  int t = threadIdx.x;
  int wid = t >> 6, lane = t & 63;
  int wr = wid >> 1, wc = wid & 1;
  // ---- stage A = normalized e (bf16) ----
  {
    int i = t >> 1, half = t & 1;
    size_t pix = (MODE == 0) ? ((size_t)i * F_W + x) : ((size_t)x * F_W + i);
    float rv = 1.0f / (sumH[base + pix] + sumW[base + pix]);
    const unsigned short* ep = eb + (base + pix) * 256 + MODE * 128 + half * 64;
    int g = ((i >> 3) & 7) ^ (i & 7);
#pragma unroll
    for (int s = 0; s < 8; s++) {
      short8 vin = *(const short8*)(ep + s * 8);
      short8 vo;
#pragma unroll
      for (int j = 0; j < 8; j++) vo[j] = (short)f2bf(bf2f((unsigned short)vin[j]) * rv);
      int slot = (half * 8 + s) ^ g;  // g is 3-bit: half bit preserved
      *(short8*)(As + i * 128 + slot * 8) = vo;
    }
  }
  float4v acc[4][8] = {};
#pragma unroll
  for (int kc = 0; kc < 2; kc++) {
    __syncthreads();
    // ---- stage Vs[c][k] for k-chunk kc: in-register 8x8 transpose ----
    {
      int ko = t >> 5, cj = t & 31;
      short8 rowv[8];
#pragma unroll
      for (int r = 0; r < 8; r++) {
        int kk = kc * 64 + ko * 8 + r;
        size_t pixk = (MODE == 0) ? ((size_t)kk * F_W + x) : ((size_t)x * F_W + kk);
        rowv[r] = *(const short8*)(vtb + (base + pixk) * 256 + cj * 8);
      }
#pragma unroll
      for (int j = 0; j < 8; j++) {
        short8 col;
#pragma unroll
        for (int r = 0; r < 8; r++) col[r] = rowv[r][j];
        int c = cj * 8 + j;
        int slot = ko ^ ((c >> 3) & 7) ^ (c & 7);
        *(short8*)(Vs + c * 64 + slot * 8) = col;
      }
    }
    __syncthreads();
#pragma unroll
    for (int ksub = 0; ksub < 2; ksub++) {
      short8 af[4];
#pragma unroll
      for (int mi = 0; mi < 4; mi++) {
        int i = wr * 64 + mi * 16 + (lane & 15);
        int slot = (kc * 8 + ksub * 4 + (lane >> 4)) ^ ((i >> 3) & 7) ^ (i & 7);
        af[mi] = *(const short8*)(As + i * 128 + slot * 8);
      }
      short8 bfv[8];
#pragma unroll
      for (int ni = 0; ni < 8; ni++) {
        int c = wc * 128 + ni * 16 + (lane & 15);
        int slot = (ksub * 4 + (lane >> 4)) ^ ((c >> 3) & 7) ^ (c & 7);
        bfv[ni] = *(const short8*)(Vs + c * 64 + slot * 8);
      }
#pragma unroll
      for (int mi = 0; mi < 4; mi++)
#pragma unroll
        for (int ni = 0; ni < 8; ni++)
          acc[mi][ni] =
              __builtin_amdgcn_mfma_f32_16x16x32_bf16(af[mi], bfv[ni], acc[mi][ni], 0, 0, 0);
    }
  }
  // ---- epilogue ----
  float gm = gamma[0];
#pragma unroll
  for (int mi = 0; mi < 4; mi++) {
#pragma unroll
    for (int ni = 0; ni < 8; ni++) {
#pragma unroll
      for (int r = 0; r < 4; r++) {
        int i = wr * 64 + mi * 16 + (lane >> 4) * 4 + r;
        int c = wc * 128 + ni * 16 + (lane & 15);
        size_t pix = (MODE == 0) ? ((size_t)i * F_W + x) : ((size_t)x * F_W + i);
        size_t idx = (base + pix) * 256 + c;
        if (MODE == 0) {
          pob[idx] = f2bf(acc[mi][ni][r]);
        } else {
          float v = gm * (bf2f(pob[idx]) + acc[mi][ni][r]) + bf2f(xb[idx]);
          ccb[idx] = f2bf(v);
        }
      }
    }
  }
}

// ---------------- FUSED window qkv-GEMM + attention (head-aligned waves) ----
// One block per window, 512 threads = 8 waves (wave = head). LDS 128 KiB:
//   As (window cc, 32K) | Bs per-wave dbuf 2 groups (8 x 2 x 2KB = 32K) |
//   QKV q|k only (64K).  V never hits QKV: wave wid computes head wid's 32 v
//   channels and writes them DIRECTLY into the transposed Vt layout after the
//   barrier (As overlay).  Per k-step: 4 As reads amortized over 2 col-groups
//   -> 6 ds_read_b128 : 8 MFMA (was 5:4).  Zero barriers inside the k-loops.
__global__ __launch_bounds__(512, 2) void win_fused(
    const unsigned short* __restrict__ ccb, const unsigned short* __restrict__ qkv_wb,
    const float* __restrict__ qkv_b, const float* __restrict__ logit_scale,
    const float* __restrict__ rpbt, unsigned short* __restrict__ out) {
  __shared__ __align__(16) unsigned short As[64 * 256];       // 32 KB
  __shared__ __align__(16) unsigned short Bs[8][2][1024];     // 32 KB
  __shared__ __align__(16) unsigned short QKV[2 * 64 * 256];  // 64 KB (q|k)
  int tid = threadIdx.x;
  int wid = tid >> 6, lane = tid & 63;
  int il = lane & 15, kg = lane >> 4;
  int win = blockIdx.x;
  int b = win >> 8, wy = (win >> 4) & 15, wx = win & 15;
  size_t pbase = (size_t)b * F_HW + (size_t)(wy * 8) * F_W + wx * 8;

  // ---- stage As: window cc rows [n][c], swizzle slot = (c>>3) ^ (n&7) ----
#pragma unroll
  for (int i = 0; i < 4; i++) {
    int n = i * 16 + (tid >> 5);
    int slot = tid & 31;
    size_t srow = pbase + (size_t)(n >> 3) * F_W + (n & 7);
    async_copy16(ccb + srow * 256 + (size_t)(slot ^ (n & 7)) * 8, As + n * 256 + slot * 8);
  }
  __syncthreads();

  // ---- per-wave GEMM: sec 0=q,1=k,2=v; wave owns cols sec*256+wid*32+{0..31}
  int r16 = lane >> 2, ks = lane & 3;
  int kgB = ks ^ ((r16 >> 1) & 3);  // inverse swizzle on global source
  unsigned short* Bw = &Bs[wid][0][0];
  float4v a0[4], a1[4];
  for (int sec = 0; sec < 3; sec++) {
    const unsigned short* wp = qkv_wb + (size_t)(sec * 256 + wid * 32 + r16) * 256 + kgB * 8;
    async_copy16(wp, Bw + lane * 8);              // buf0 group0
    async_copy16(wp + 16 * 256, Bw + 512 + lane * 8);  // buf0 group1
#pragma unroll
    for (int mi = 0; mi < 4; mi++) {
      float4v z = {0.0f, 0.0f, 0.0f, 0.0f};
      a0[mi] = z;
      a1[mi] = z;
    }
    int cur = 0;
    for (int k0 = 0; k0 < 256; k0 += 32) {
      int swB = (kg ^ ((il >> 1) & 3)) * 8;
      short8 bf0 = *(const short8*)(Bw + cur * 1024 + il * 32 + swB);
      short8 bf1 = *(const short8*)(Bw + cur * 1024 + 512 + il * 32 + swB);
      short8 af[4];
#pragma unroll
      for (int mi = 0; mi < 4; mi++) {
        int row = mi * 16 + il;
        int slot = ((k0 >> 3) + kg) ^ (row & 7);
        af[mi] = *(const short8*)(As + row * 256 + slot * 8);
      }
      if (k0 < 224) {
        async_copy16(wp + k0 + 32, Bw + (cur ^ 1) * 1024 + lane * 8);
        async_copy16(wp + 16 * 256 + k0 + 32, Bw + (cur ^ 1) * 1024 + 512 + lane * 8);
      }
      __builtin_amdgcn_s_setprio(1);
#pragma unroll
      for (int mi = 0; mi < 4; mi++)
        a0[mi] = __builtin_amdgcn_mfma_f32_16x16x32_bf16(bf0, af[mi], a0[mi], 0, 0, 0);
#pragma unroll
      for (int mi = 0; mi < 4; mi++)
        a1[mi] = __builtin_amdgcn_mfma_f32_16x16x32_bf16(bf1, af[mi], a1[mi], 0, 0, 0);
      __builtin_amdgcn_s_setprio(0);
      cur ^= 1;
    }
    if (sec < 2) {
      // epilogue -> QKV LDS (bf16 + bias); pixel n = mi*16+il, 4 cols/lane
      unsigned short* qp = QKV + sec * 16384;
#pragma unroll
      for (int g = 0; g < 2; g++) {
        int cs = wid * 32 + g * 16 + kg * 4;
        float4 bn4 = *(const float4*)(qkv_b + sec * 256 + cs);
        float bns[4] = {bn4.x, bn4.y, bn4.z, bn4.w};
#pragma unroll
        for (int mi = 0; mi < 4; mi++) {
          int n = mi * 16 + il;
          short4v pk;
#pragma unroll
          for (int r = 0; r < 4; r++) pk[r] = (short)f2bf((g ? a1 : a0)[mi][r] + bns[r]);
          *(short4v*)(qp + n * 256 + (((cs >> 3) ^ (n & 7)) * 8) + (cs & 7)) = pk;
        }
      }
    }
  }
  // a0/a1 hold the v-section results for head wid
  __syncthreads();  // all As reads + q/k writes complete

  int hh = wid;
  unsigned short* Pl_w = QKV + wid * 4096;  // overlays q+k (dead after S)
  unsigned short* Vt_w = As + wid * 2048;   // overlays As (dead after GEMM)

  // ---- direct V -> Vt transposed write (d = head channel, j = pixel) ----
#pragma unroll
  for (int g = 0; g < 2; g++) {
    int cs = wid * 32 + g * 16 + kg * 4;
    float4 bn4 = *(const float4*)(qkv_b + 512 + cs);
    float bns[4] = {bn4.x, bn4.y, bn4.z, bn4.w};
#pragma unroll
    for (int mi = 0; mi < 4; mi++) {
      int n = mi * 16 + il;
#pragma unroll
      for (int r = 0; r < 4; r++) {
        int d = g * 16 + kg * 4 + r;
        Vt_w[d * 64 + (((n >> 3) ^ (d & 7)) * 8) + (n & 7)] =
            f2bf((g ? a1 : a0)[mi][r] + bns[r]);
      }
    }
  }

  // ---- load + cosine-normalize Q (B-frags) and K (A-frags) from LDS ----
  short8 qb[4], ka[4];
#pragma unroll
  for (int ni = 0; ni < 4; ni++) {
    int i = ni * 16 + il;
    int so = ((hh * 4 + kg) ^ (i & 7)) * 8;
    short8 qv = *(const short8*)(QKV + i * 256 + so);
    short8 kv = *(const short8*)(QKV + 16384 + i * 256 + so);
    float qss = 0.0f, kss = 0.0f;
#pragma unroll
    for (int j = 0; j < 8; j++) {
      float qf = bf2f((unsigned short)qv[j]);
      float kf = bf2f((unsigned short)kv[j]);
      qss += qf * qf;
      kss += kf * kf;
    }
    qss += __shfl_xor(qss, 16);
    qss += __shfl_xor(qss, 32);
    kss += __shfl_xor(kss, 16);
    kss += __shfl_xor(kss, 32);
    float qinv = 1.0f / fmaxf(sqrtf(qss), 1e-12f);
    float kinv = 1.0f / fmaxf(sqrtf(kss), 1e-12f);
#pragma unroll
    for (int j = 0; j < 8; j++) {
      qb[ni][j] = (short)f2bf(bf2f((unsigned short)qv[j]) * qinv);
      ka[ni][j] = (short)f2bf(bf2f((unsigned short)kv[j]) * kinv);
    }
  }

  // ---- S^T = K @ Q^T ----
  float4v sacc[4][4] = {};
#pragma unroll
  for (int mj = 0; mj < 4; mj++)
#pragma unroll
    for (int ni = 0; ni < 4; ni++)
      sacc[mj][ni] =
          __builtin_amdgcn_mfma_f32_16x16x32_bf16(ka[mj], qb[ni], sacc[mj][ni], 0, 0, 0);

  float scale = __expf(fminf(logit_scale[hh], 4.605170185988091f));  // ln(100)
  __syncthreads();  // all waves done reading q,k before Pl overlay writes

  // ---- softmax over j (per col i), write P[i][j] bf16 to Pl ----
#pragma unroll
  for (int ni = 0; ni < 4; ni++) {
    int i = ni * 16 + il;
    const float* rp = rpbt + ((size_t)hh * 64 + i) * 64;
    float sv[16];
    float mx = -1e30f;
#pragma unroll
    for (int mj = 0; mj < 4; mj++) {
      float4 rb = *(const float4*)(rp + mj * 16 + kg * 4);
      float rbs[4] = {rb.x, rb.y, rb.z, rb.w};
#pragma unroll
      for (int r = 0; r < 4; r++) {
        float v = sacc[mj][ni][r] * scale + rbs[r];
        sv[mj * 4 + r] = v;
        mx = fmaxf(mx, v);
      }
    }
    mx = fmaxf(mx, __shfl_xor(mx, 16));
    mx = fmaxf(mx, __shfl_xor(mx, 32));
    float sm = 0.0f;
#pragma unroll
    for (int u = 0; u < 16; u++) {
      sv[u] = __expf(sv[u] - mx);
      sm += sv[u];
    }
    sm += __shfl_xor(sm, 16);
    sm += __shfl_xor(sm, 32);
    float inv = 1.0f / sm;
#pragma unroll
    for (int mj = 0; mj < 4; mj++) {
      int j0 = mj * 16 + kg * 4;
      short4v pk;
#pragma unroll
      for (int r = 0; r < 4; r++) pk[r] = (short)f2bf(sv[mj * 4 + r] * inv);
      int byteoff = i * 128 + (((j0 >> 3) ^ (i & 7)) * 16) + (j0 & 7) * 2;
      *(short4v*)((char*)Pl_w + byteoff) = pk;
    }
  }
  __syncthreads();

  // ---- O^T = V^T @ P^T ----
  float4v oacc[2][4] = {};
#pragma unroll
  for (int kc = 0; kc < 2; kc++) {
    short8 va[2];
#pragma unroll
    for (int md = 0; md < 2; md++) {
      int d = md * 16 + il;
      va[md] = *(const short8*)((char*)Vt_w + d * 128 + (((kc * 4 + kg) ^ (d & 7)) * 16));
    }
    short8 pb[4];
#pragma unroll
    for (int ni = 0; ni < 4; ni++) {
      int i = ni * 16 + il;
      pb[ni] = *(const short8*)((char*)Pl_w + i * 128 + (((kc * 4 + kg) ^ (i & 7)) * 16));
    }
#pragma unroll
    for (int md = 0; md < 2; md++)
#pragma unroll
      for (int ni = 0; ni < 4; ni++)
        oacc[md][ni] =
            __builtin_amdgcn_mfma_f32_16x16x32_bf16(va[md], pb[ni], oacc[md][ni], 0, 0, 0);
  }

  // ---- write out: O^T col = i = lane&15, row d = md*16 + kg*4 + r ----
#pragma unroll
  for (int ni = 0; ni < 4; ni++) {
    int i = ni * 16 + il;
    size_t orow = (pbase + (size_t)(i >> 3) * F_W + (i & 7)) * 256 + hh * 32;
#pragma unroll
    for (int md = 0; md < 2; md++) {
      int d0 = md * 16 + kg * 4;
      short4v pk;
#pragma unroll
      for (int r = 0; r < 4; r++) pk[r] = (short)f2bf(oacc[md][ni][r]);
      *(short4v*)(out + orow + d0) = pk;
    }
  }
}

// ---------------- launch ----------------
extern "C" void kernel_launch(void* const* d_in, const int* in_sizes, int n_in,
                              void* d_out, int out_size, void* d_ws, size_t ws_size,
                              hipStream_t stream) {
  const float* x = (const float*)d_in[0];
  const float* y = (const float*)d_in[1];
  const float* Wq = (const float*)d_in[2];
  const float* bq = (const float*)d_in[3];
  const float* Wk = (const float*)d_in[4];
  const float* bk = (const float*)d_in[5];
  const float* Wv = (const float*)d_in[6];
  const float* bv = (const float*)d_in[7];
  const float* gamma = (const float*)d_in[8];
  const float* qkv_w = (const float*)d_in[9];
  const float* q_bias = (const float*)d_in[10];
  const float* v_bias = (const float*)d_in[11];
  const float* logit_scale = (const float*)d_in[12];
  const float* cpb_w1 = (const float*)d_in[13];
  const float* cpb_b1 = (const float*)d_in[14];
  const float* cpb_w2 = (const float*)d_in[15];
  const float* proj_w = (const float*)d_in[16];
  const float* proj_b = (const float*)d_in[17];

  float* ws = (float*)d_ws;
  const size_t NPX = (size_t)F_B * F_HW;  // 131072
  const size_t M1 = NPX * 256;            // 33.55M floats (bf16 plane = M1/2 floats)
  size_t f_xb = 0;                 // xb bf16
  size_t f_ytb = M1 / 2;           // ytb bf16; eb bf16 overlays after v-GEMM
  size_t f_vtb = M1;               // vtb bf16
  size_t f_pob = M1 + M1 / 2;      // pob bf16; attn_b bf16 overlays after pv
  size_t f_ccb = 2 * M1;           // ccb bf16
  size_t f_qkb = 2 * M1 + M1 / 2;  // qkb fp32 (NPX*64)
  size_t f_wts = f_qkb + NPX * 64;
  size_t o_qkwb = f_wts;              // 16384 ushort -> 8192 f
  size_t o_Wvb = o_qkwb + 8192;       // 65536 ushort -> 32768 f
  size_t o_qkvwb = o_Wvb + 32768;     // 196608 ushort -> 98304 f
  size_t o_projwb = o_qkvwb + 98304;  // 65536 ushort -> 32768 f
  size_t o_qkb2 = o_projwb + 32768;   // 64 f
  size_t o_qkvb2 = o_qkb2 + 64;       // 768 f
  size_t o_tbl = o_qkvb2 + 768;       // 1800 f
  size_t o_sumH = o_tbl + 1800;       // NPX f
  size_t o_sumW = o_sumH + NPX;       // NPX f
  size_t o_rpbt = o_sumW + NPX;       // 32768 f
  size_t need = (o_rpbt + 32768) * sizeof(float);
  if (ws_size < need) {
    fprintf(stderr, "kernel_launch: ws too small: %zu < %zu\n", ws_size, need);
    return;
  }
  unsigned short* xb = (unsigned short*)(ws + f_xb);
  unsigned short* ytb = (unsigned short*)(ws + f_ytb);
  unsigned short* eb = (unsigned short*)(ws + f_ytb);
  unsigned short* vtb = (unsigned short*)(ws + f_vtb);
  unsigned short* pob = (unsigned short*)(ws + f_pob);
  unsigned short* attn_b = (unsigned short*)(ws + f_pob);
  unsigned short* ccb = (unsigned short*)(ws + f_ccb);
  float* qkb = ws + f_qkb;
  unsigned short* qk_wb = (unsigned short*)(ws + o_qkwb);
  unsigned short* Wvb = (unsigned short*)(ws + o_Wvb);
  unsigned short* qkv_wb = (unsigned short*)(ws + o_qkvwb);
  unsigned short* proj_wb = (unsigned short*)(ws + o_projwb);
  float* qk_b = ws + o_qkb2;
  float* qkv_b = ws + o_qkvb2;
  float* tblS = ws + o_tbl;
  float* sumH = ws + o_sumH;
  float* sumW = ws + o_sumW;
  float* rpbt = ws + o_rpbt;

  build_aux2<<<dim3(768), dim3(256), 0, stream>>>(Wq, Wk, bq, bk, q_bias, v_bias, Wv, qkv_w,
                                                  proj_w, qk_wb, qk_b, qkv_b, Wvb, qkv_wb,
                                                  proj_wb);
  cpb_table<<<dim3(225), dim3(256), 0, stream>>>(cpb_w1, cpb_b1, cpb_w2, tblS);
  build_rpbt<<<dim3(128), dim3(256), 0, stream>>>(tblS, rpbt);
  // x^T -> xb bf16 ; y^T -> ytb bf16
  transpose_bf<<<dim3(512, 8, 8), dim3(32, 8), 0, stream>>>(x, xb);
  transpose_bf<<<dim3(512, 8, 8), dim3(32, 8), 0, stream>>>(y, ytb);
  // q|k projection: (BHW x 256) @ (64 x 256)^T -> fp32
  gemm_mfma<64, 0><<<dim3(1024), dim3(256), 0, stream>>>(xb, qk_wb, qk_b, qkb, (int)NPX, 64,
                                                         1);
  // v projection -> bf16 vtb
  gemm_mfma<128, 2><<<dim3(2048), dim3(256), 0, stream>>>(ytb, Wvb, bv, vtb, (int)NPX, 256, 2);
  // criss-cross attention (GEMM-structured, bf16 e, fused partial sums)
  cc_logits<0><<<dim3(128, 8), dim3(256), 0, stream>>>(qkb, eb, sumH);
  cc_logits<1><<<dim3(128, 8), dim3(256), 0, stream>>>(qkb, eb, sumW);
  cc_pv_mfma<0><<<dim3(128, 8), dim3(256), 0, stream>>>(eb, vtb, sumH, sumW, gamma, xb, pob,
                                                        ccb);
  cc_pv_mfma<1><<<dim3(128, 8), dim3(256), 0, stream>>>(eb, vtb, sumH, sumW, gamma, xb, pob,
                                                        ccb);
  // FUSED window qkv projection + window attention (head-aligned waves)
  win_fused<<<dim3(2048), dim3(512), 0, stream>>>(ccb, qkv_wb, qkv_b, logit_scale, rpbt,
                                                  attn_b);
  // output projection with transposed (B,C,H,W) write
  gemm_mfma<128, 1><<<dim3(2048), dim3(256), 0, stream>>>(attn_b, proj_wb, proj_b, d_out,
                                                          (int)NPX, 256, 2);
}